// Round 8
// baseline (6652.248 us; speedup 1.0000x reference)
//
#include <hip/hip_runtime.h>
#include <math.h>

#define SS 512
#define AANG 60
#define DDET 729
#define NPIX (SS*SS)        // 262144
#define NSIN (AANG*DDET)    // 43740
#define NTAPS 1457
#define DRS 768             // dual NHWC padded row stride

typedef float v4u __attribute__((ext_vector_type(4), aligned(4)));
typedef float v2u __attribute__((ext_vector_type(2), aligned(8)));
typedef short short8 __attribute__((ext_vector_type(8)));
typedef short short4v __attribute__((ext_vector_type(4)));
typedef float f32x4 __attribute__((ext_vector_type(4)));

// round-to-nearest-even fp32 -> bf16 bits
__device__ inline unsigned short f2bf(float x){
  unsigned u = __float_as_uint(x);
  return (unsigned short)((u + 0x7fffu + ((u >> 16) & 1u)) >> 16);
}

__device__ inline unsigned pack_hilo(float x){
  unsigned short hb = f2bf(x);
  float hf = __uint_as_float((unsigned)hb << 16);
  unsigned short lb = f2bf(x - hf);
  return ((unsigned)hb << 16) | (unsigned)lb;
}

// software grid barrier (all blocks co-resident by construction)
__device__ inline void gbar(int* cnt, int target){
  __syncthreads();
  __threadfence();
  if (threadIdx.x == 0){
    atomicAdd(cnt, 1);
    while (atomicAdd(cnt, 0) < target) __builtin_amdgcn_s_sleep(1);
  }
  __syncthreads();
  __threadfence();
}

// ---------------- trig table ----------------
__global__ void trig_kernel(const float* __restrict__ theta, float* __restrict__ trig){
  int a = threadIdx.x;
  if (a < AANG){ trig[a] = cosf(theta[a]); trig[AANG+a] = sinf(theta[a]); }
}

// ---------------- ramp-filter taps ----------------
__global__ void taps_kernel(float* __restrict__ taps){
  __shared__ double red[256];
  int m  = blockIdx.x;
  int mm = m - 728;
  double s = 0.0;
  for (int k = 1 + (int)threadIdx.x; k <= 1023; k += 256){
    int phase = (k*mm) & 2047;
    s += (double)k * cos((double)phase * (M_PI/1024.0));
  }
  red[threadIdx.x] = s;
  __syncthreads();
  for (int off=128; off; off>>=1){
    if ((int)threadIdx.x < off) red[threadIdx.x] += red[threadIdx.x+off];
    __syncthreads();
  }
  if (threadIdx.x==0){
    double x = (red[0]*(1.0/512.0) + ((mm & 1) ? -1.0 : 1.0)) / 2048.0;
    taps[m] = (float)(x * (M_PI/120.0));
  }
}

// -------- MFMA B-fragment image: [L][tap=9][n=2][prod=2][lane=64][8] bf16 --------
__global__ void prep_bimg(const float* __restrict__ w, unsigned short* __restrict__ B){
  int idx = blockIdx.x*256 + (int)threadIdx.x;
  if (idx >= 10*9*2*64*8) return;
  int j    =  idx        & 7;
  int lane = (idx >> 3)  & 63;
  int n    = (idx >> 9)  & 1;
  int r    =  idx >> 10;          // l*9 + tap
  int tap = r % 9, l = r / 9;
  int c = (lane >> 4)*8 + j;      // k = channel
  int o = n*16 + (lane & 15);     // output channel
  float x = w[(((size_t)(l*32+o)*32 + c)*9) + tap];
  unsigned short hb = f2bf(x);
  float hf = __uint_as_float((unsigned)hb << 16);
  unsigned short lb = f2bf(x - hf);
  size_t d = (size_t)l*18432 + (size_t)tap*2048 + n*1024 + lane*8 + j;
  B[d]       = hb;
  B[d + 512] = lb;
}

// -------- MFMA B-fragment image for [L][5][32][3][3]: [L][tap=9][prod=2][lane=64][8] --------
__global__ void prep_bimg3(const float* __restrict__ w, unsigned short* __restrict__ B){
  int idx = blockIdx.x*256 + (int)threadIdx.x;
  if (idx >= 10*9*64*8) return;
  int j    =  idx       & 7;
  int lane = (idx >> 3) & 63;
  int r    =  idx >> 9;           // l*9 + tap
  int tap = r % 9, l = r / 9;
  int c = (lane >> 4)*8 + j;      // k = channel
  int o = lane & 15;              // output channel (5 real)
  float x = (o < 5) ? w[(((size_t)(l*5+o)*32 + c)*9) + tap] : 0.f;
  unsigned short hb = f2bf(x);
  float hf = __uint_as_float((unsigned)hb << 16);
  unsigned short lb = f2bf(x - hf);
  size_t d = (size_t)l*9216 + (size_t)tap*1024 + lane*8 + j;
  B[d]       = hb;
  B[d + 512] = lb;
}

// -------- MFMA B-fragment image for NHWC8 conv1 weights [L][32][Cin][3][3] --------
__global__ void prep_bimg1c(const float* __restrict__ w, unsigned short* __restrict__ B, int Cin){
  int idx = blockIdx.x*256 + (int)threadIdx.x;
  if (idx >= 10*3*2*64*8) return;
  int j    =  idx       & 7;
  int lane = (idx >> 3) & 63;
  int n    = (idx >> 9) & 1;
  int r    =  idx >> 10;          // l*3 + g
  int g = r % 3, l = r / 3;
  int t = g*4 + (lane >> 4);
  int o = n*16 + (lane & 15);
  float x = (t < 9 && j < Cin) ? w[(((size_t)(l*32+o)*Cin + j)*9) + t] : 0.f;
  unsigned short hb = f2bf(x);
  float hf = __uint_as_float((unsigned)hb << 16);
  unsigned short lb = f2bf(x - hf);
  size_t d = (size_t)l*6144 + (size_t)g*2048 + n*1024 + lane*8 + j;
  B[d]       = hb;
  B[d + 512] = lb;
}

// ---------------- g -> sinogram NHWC8 ch6 (once) ----------------
__global__ void g_to_nhwc8(const float* __restrict__ g,
                           unsigned short* __restrict__ s8hi, unsigned short* __restrict__ s8lo){
  int idx = blockIdx.x*256 + (int)threadIdx.x;
  if (idx >= NSIN) return;
  int a = idx / DDET, d = idx - a*DDET;
  float x = g[idx];
  unsigned p = pack_hilo(x);
  size_t p8 = ((size_t)(a+1)*DRS + d)*8 + 6;
  s8hi[p8] = (unsigned short)(p >> 16);
  s8lo[p8] = (unsigned short)(p & 0xffffu);
}

// ---------------- radon forward: rcp-hoisted clip; writes NHWC8sin ch5 ----------------
__device__ inline void clipr(float al, float ial, float be, float lo, float hi,
                             float& A, float& B, bool& empty){
  if (fabsf(al) < 1e-7f){ if (be < lo || be > hi) empty = true; return; }
  float t0 = (lo - be)*ial, t1 = (hi - be)*ial;
  float mn = fminf(t0,t1), mx = fmaxf(t0,t1);
  A = fmaxf(A, mn); B = fminf(B, mx);
}

__device__ inline float samp_guard(const float* __restrict__ base, float aR, float bR,
                                   float aC, float bC, int t){
  float tp = (float)t - 255.5f;
  float R = fmaf(aR, tp, bR);
  float C = fmaf(aC, tp, bC);
  float rf = floorf(R), cf = floorf(C);
  int r0 = (int)rf, c0 = (int)cf;
  int r1 = r0+1,    c1 = c0+1;
  float fr = R - rf, fc = C - cf;
  bool r0ok = (r0>=0 && r0<SS), r1ok = (r1>=0 && r1<SS);
  bool c0ok = (c0>=0 && c0<SS), c1ok = (c1>=0 && c1<SS);
  float v00 = (r0ok && c0ok) ? base[r0*SS+c0] : 0.f;
  float v01 = (r0ok && c1ok) ? base[r0*SS+c1] : 0.f;
  float v10 = (r1ok && c0ok) ? base[r1*SS+c0] : 0.f;
  float v11 = (r1ok && c1ok) ? base[r1*SS+c1] : 0.f;
  return (1.f-fr)*((1.f-fc)*v00 + fc*v01) + fr*((1.f-fc)*v10 + fc*v11);
}

__global__ __launch_bounds__(256) void radon_fwd_kernel(
    const float* __restrict__ img, const float* __restrict__ imgT,
    const float* __restrict__ trig,
    unsigned short* __restrict__ s8hi, unsigned short* __restrict__ s8lo){
  int gid  = blockIdx.x*4 + ((int)threadIdx.x >> 6);
  int lane = (int)threadIdx.x & 63;
  if (gid >= NSIN) return;
  int a = gid / DDET;
  int d = gid - a*DDET;
  float ca = trig[a], sa = trig[AANG+a];
  float sd = (float)d - 364.0f;
  float Rc = fmaf(sd, sa, 255.5f);
  float Cc = fmaf(sd, ca, 255.5f);
  float aR = ca, bR = Rc, aC = -sa, bC = Cc;
  const float* base = img;
  if (fabsf(ca) > fabsf(sa)){
    base = imgT;
    float tmp;
    tmp=aR; aR=aC; aC=tmp;
    tmp=bR; bR=bC; bC=tmp;
  }
  float iaR = __builtin_amdgcn_rcpf(aR);
  float iaC = __builtin_amdgcn_rcpf(aC);
  float tiA = -255.5f, tiB = 255.5f;  bool iE=false;
  float teA = -255.5f, teB = 255.5f;  bool eE=false;
  clipr(aR,iaR,bR, 0.001f, 510.999f, tiA,tiB,iE);
  clipr(aC,iaC,bC, 0.001f, 510.999f, tiA,tiB,iE);
  clipr(aR,iaR,bR, -0.999f, 511.999f, teA,teB,eE);
  clipr(aC,iaC,bC, -0.999f, 511.999f, teA,teB,eE);
  float acc = 0.f;
  if (!eE && teA <= teB){
    int eA = max(0,   (int)floorf(teA+255.5f) - 1);
    int eB = min(511, (int)ceilf (teB+255.5f) + 1);
    int iA = (int)ceilf (tiA+255.5f) + 1;
    int iB = (int)floorf(tiB+255.5f) - 1;
    iA = max(iA, eA); iB = min(iB, eB);
    if (iE || iA > iB){
      for (int t = eA+lane; t <= eB; t += 64) acc += samp_guard(base,aR,bR,aC,bC,t);
    } else {
      for (int t = eA+lane;   t <  iA; t += 64) acc += samp_guard(base,aR,bR,aC,bC,t);
      for (int t = iB+1+lane; t <= eB; t += 64) acc += samp_guard(base,aR,bR,aC,bC,t);
      for (int t = iA+lane;   t <= iB; t += 64){
        float tp = (float)t - 255.5f;
        float R = fmaf(aR, tp, bR);
        float C = fmaf(aC, tp, bC);
        int r0 = (int)R, c0 = (int)C;
        float fr = R - (float)r0, fc = C - (float)c0;
        const float* p = base + r0*SS + c0;
        float v00 = p[0], v01 = p[1], v10 = p[SS], v11 = p[SS+1];
        float top = v00 + fc*(v01-v00);
        float bot = v10 + fc*(v11-v10);
        acc += top + fr*(bot-top);
      }
    }
  }
  for (int off=32; off; off>>=1) acc += __shfl_down(acc, off);
  if (lane==0){
    unsigned p = pack_hilo(acc);
    size_t p8 = ((size_t)(a+1)*DRS + d)*8 + 5;
    s8hi[p8] = (unsigned short)(p >> 16);
    s8lo[p8] = (unsigned short)(p & 0xffffu);
  }
}

// ---------------- FUSED dual chain: conv1 -> conv2 -> conv3 -> ramp filter ----------------
// grid 720 x 256thr; __launch_bounds__(256,3) guarantees >=3 blocks/CU = 768 >= 720 co-resident
__global__ __launch_bounds__(256, 3) void dual_chain(
    unsigned short* __restrict__ s8hi, unsigned short* __restrict__ s8lo,   // [62][DRS][8]
    unsigned short* __restrict__ d1hi, unsigned short* __restrict__ d1lo,   // [62][DRS][32]
    unsigned short* __restrict__ d2hi, unsigned short* __restrict__ d2lo,   // [62][DRS][32]
    const unsigned short* __restrict__ B1,   // [3][2][2][64][8]
    const unsigned short* __restrict__ B2,   // [9][2][2][64][8]
    const unsigned short* __restrict__ B3,   // [9][2][64][8]
    const float* __restrict__ b1, const float* __restrict__ a1,
    const float* __restrict__ b2, const float* __restrict__ a2,
    const float* __restrict__ b3,
    float* __restrict__ h, float* __restrict__ h1,
    const float* __restrict__ taps,
    int* __restrict__ cnt)
{
  __shared__ unsigned int tr[64][33];
  __shared__ unsigned int t8[64][6];
  __shared__ float red[256];
  int tid = (int)threadIdx.x;
  int wv = tid >> 6, lane = tid & 63;
  int bid = (int)blockIdx.x;
  int y = bid / 12, xc = bid - y*12;
  int xw = xc * 64;
  int lm = lane & 15, lq = lane >> 4;
  int laneoff = lm*32 + lq*8;

  // ======== phase A: dual conv1 (7->32), s-subtile = wave ========
  {
    f32x4 acc0 = (f32x4)0.f, acc1 = (f32x4)0.f;
    const short8* Bf = (const short8*)B1;
    #pragma unroll
    for (int g=0; g<3; g++){
      const short8* bp8 = Bf + g*256 + lane;
      short8 bh0 = bp8[0], bl0 = bp8[64], bh1 = bp8[128], bl1 = bp8[192];
      int t = g*4 + lq; if (t > 8) t = 8;
      int dy = (t >= 6) ? 1 : ((t >= 3) ? 0 : -1);
      int dx = t - (dy+1)*3 - 1;
      int row = y + dy + 1;
      int px = xw + wv*16 + lm + dx;
      size_t off = (size_t)(row*DRS + px)*8;
      short8 ah = *(const short8*)(s8hi + off);
      short8 al = *(const short8*)(s8lo + off);
      acc0 = __builtin_amdgcn_mfma_f32_16x16x32_bf16(ah, bh0, acc0, 0,0,0);
      acc1 = __builtin_amdgcn_mfma_f32_16x16x32_bf16(ah, bh1, acc1, 0,0,0);
      acc0 = __builtin_amdgcn_mfma_f32_16x16x32_bf16(al, bh0, acc0, 0,0,0);
      acc1 = __builtin_amdgcn_mfma_f32_16x16x32_bf16(al, bh1, acc1, 0,0,0);
      acc0 = __builtin_amdgcn_mfma_f32_16x16x32_bf16(ah, bl0, acc0, 0,0,0);
      acc1 = __builtin_amdgcn_mfma_f32_16x16x32_bf16(ah, bl1, acc1, 0,0,0);
    }
    float aa = *a1;
    #pragma unroll
    for (int n=0;n<2;n++){
      int o = n*16 + lm;
      float bv = b1[o];
      f32x4 v = n ? acc1 : acc0;
      v.x+=bv; v.y+=bv; v.z+=bv; v.w+=bv;
      v.x=(v.x>=0.f)?v.x:aa*v.x; v.y=(v.y>=0.f)?v.y:aa*v.y;
      v.z=(v.z>=0.f)?v.z:aa*v.z; v.w=(v.w>=0.f)?v.w:aa*v.w;
      #pragma unroll
      for (int r=0;r<4;r++) tr[wv*16 + lq*4 + r][o] = pack_hilo(v[r]);
    }
  }
  __syncthreads();
  {
    int c8 = tid & 3;
    int px = tid >> 2;
    int x = xw + px;
    if (x <= 728){
      short8 vh, vl;
      #pragma unroll
      for (int j=0;j<8;j++){
        unsigned p = tr[px][c8*8 + j];
        vh[j] = (short)(p >> 16);
        vl[j] = (short)(p & 0xffffu);
      }
      size_t base = ((size_t)(y+1)*DRS + x)*32 + c8*8;
      *(short8*)(d1hi + base) = vh;
      *(short8*)(d1lo + base) = vl;
    }
  }
  gbar(cnt, 720);

  // ======== phase B: dual conv2 (32->32), s-subtile = wave ========
  {
    f32x4 acc0 = (f32x4)0.f, acc1 = (f32x4)0.f;
    const short8* Bf = (const short8*)B2;
    #pragma unroll
    for (int dy=-1; dy<=1; dy++){
      const unsigned short* rh = d1hi + (size_t)(y+dy+1)*DRS*32;
      const unsigned short* rl = d1lo + (size_t)(y+dy+1)*DRS*32;
      #pragma unroll
      for (int dx=-1; dx<=1; dx++){
        int tap = (dy+1)*3 + (dx+1);
        const short8* bp8 = Bf + tap*256 + lane;
        short8 bh0 = bp8[0], bl0 = bp8[64], bh1 = bp8[128], bl1 = bp8[192];
        int xoff = (xw + dx)*32 + laneoff + wv*512;
        short8 ah = *(const short8*)(rh + xoff);
        short8 al = *(const short8*)(rl + xoff);
        acc0 = __builtin_amdgcn_mfma_f32_16x16x32_bf16(ah, bh0, acc0, 0,0,0);
        acc1 = __builtin_amdgcn_mfma_f32_16x16x32_bf16(ah, bh1, acc1, 0,0,0);
        acc0 = __builtin_amdgcn_mfma_f32_16x16x32_bf16(al, bh0, acc0, 0,0,0);
        acc1 = __builtin_amdgcn_mfma_f32_16x16x32_bf16(al, bh1, acc1, 0,0,0);
        acc0 = __builtin_amdgcn_mfma_f32_16x16x32_bf16(ah, bl0, acc0, 0,0,0);
        acc1 = __builtin_amdgcn_mfma_f32_16x16x32_bf16(ah, bl1, acc1, 0,0,0);
      }
    }
    float aa = *a2;
    #pragma unroll
    for (int n=0;n<2;n++){
      int o = n*16 + lm;
      float bv = b2[o];
      f32x4 v = n ? acc1 : acc0;
      v.x+=bv; v.y+=bv; v.z+=bv; v.w+=bv;
      v.x=(v.x>=0.f)?v.x:aa*v.x; v.y=(v.y>=0.f)?v.y:aa*v.y;
      v.z=(v.z>=0.f)?v.z:aa*v.z; v.w=(v.w>=0.f)?v.w:aa*v.w;
      #pragma unroll
      for (int r=0;r<4;r++) tr[wv*16 + lq*4 + r][o] = pack_hilo(v[r]);
    }
  }
  __syncthreads();
  {
    int c8 = tid & 3;
    int px = tid >> 2;
    int x = xw + px;
    if (x <= 728){
      short8 vh, vl;
      #pragma unroll
      for (int j=0;j<8;j++){
        unsigned p = tr[px][c8*8 + j];
        vh[j] = (short)(p >> 16);
        vl[j] = (short)(p & 0xffffu);
      }
      size_t base = ((size_t)(y+1)*DRS + x)*32 + c8*8;
      *(short8*)(d2hi + base) = vh;
      *(short8*)(d2lo + base) = vl;
    }
  }
  gbar(cnt, 1440);

  // ======== phase C: dual conv3 (32->5), h += ; s8 ch0-4 ========
  {
    f32x4 acc = (f32x4)0.f;
    const short8* Bf = (const short8*)B3;
    #pragma unroll
    for (int dy=-1; dy<=1; dy++){
      const unsigned short* rh = d2hi + (size_t)(y+dy+1)*DRS*32;
      const unsigned short* rl = d2lo + (size_t)(y+dy+1)*DRS*32;
      #pragma unroll
      for (int dx=-1; dx<=1; dx++){
        int tap = (dy+1)*3 + (dx+1);
        const short8* bp8 = Bf + tap*128 + lane;
        short8 bh = bp8[0];
        short8 bl = bp8[64];
        int xoff = (xw + dx)*32 + laneoff + wv*512;
        short8 ah = *(const short8*)(rh + xoff);
        short8 al = *(const short8*)(rl + xoff);
        acc = __builtin_amdgcn_mfma_f32_16x16x32_bf16(ah, bh, acc, 0,0,0);
        acc = __builtin_amdgcn_mfma_f32_16x16x32_bf16(al, bh, acc, 0,0,0);
        acc = __builtin_amdgcn_mfma_f32_16x16x32_bf16(ah, bl, acc, 0,0,0);
      }
    }
    if (lm < 5){
      float bv = b3[lm];
      int px0 = xw + wv*16 + lq*4;
      float* op = h + (size_t)lm*NSIN + y*DDET + px0;
      float nv0=0.f, nv1=0.f, nv2=0.f, nv3=0.f;
      if (px0 + 3 <= 728){
        v4u old = *(const v4u*)op;
        nv0 = old.x + acc.x + bv;
        nv1 = old.y + acc.y + bv;
        nv2 = old.z + acc.z + bv;
        nv3 = old.w + acc.w + bv;
        v4u st; st.x=nv0; st.y=nv1; st.z=nv2; st.w=nv3;
        *(v4u*)op = st;
      } else {
        if (px0   <= 728){ nv0 = op[0] + acc.x + bv; op[0] = nv0; }
        if (px0+1 <= 728){ nv1 = op[1] + acc.y + bv; op[1] = nv1; }
        if (px0+2 <= 728){ nv2 = op[2] + acc.z + bv; op[2] = nv2; }
        if (px0+3 <= 728){ nv3 = op[3] + acc.w + bv; op[3] = nv3; }
      }
      float nv[4] = {nv0,nv1,nv2,nv3};
      #pragma unroll
      for (int r=0;r<4;r++) t8[wv*16 + lq*4 + r][lm] = pack_hilo(nv[r]);
    }
  }
  __syncthreads();
  if (tid < 64){
    int x = xw + tid;
    if (x <= 728){
      unsigned c0 = t8[tid][0], c1 = t8[tid][1], c2 = t8[tid][2];
      unsigned c3 = t8[tid][3], c4 = t8[tid][4];
      size_t base = ((size_t)(y+1)*DRS + x)*8;
      short4v vh; vh[0]=(short)(c0>>16); vh[1]=(short)(c1>>16); vh[2]=(short)(c2>>16); vh[3]=(short)(c3>>16);
      short4v vl; vl[0]=(short)(c0&0xffffu); vl[1]=(short)(c1&0xffffu); vl[2]=(short)(c2&0xffffu); vl[3]=(short)(c3&0xffffu);
      *(short4v*)(s8hi + base) = vh;
      *(short4v*)(s8lo + base) = vl;
      s8hi[base+4] = (unsigned short)(c4>>16);
      s8lo[base+4] = (unsigned short)(c4&0xffffu);
    }
  }
  gbar(cnt, 2160);

  // ======== phase D: ramp filter (4-way k-split, 64 outputs/block) ========
  {
    int jl = tid & 63;
    int kq = tid >> 6;
    int j  = xw + jl;
    float acc = 0.f;
    if (j < DDET){
      const float* row = h + y*DDET;
      const float* tp  = taps + 728 + j;
      int k0 = kq*183;
      int k1 = min(k0+183, DDET);
      for (int k=k0;k<k1;k++) acc = fmaf(row[k], tp[-k], acc);
    }
    red[tid] = acc;
    __syncthreads();
    if (tid < 64){
      int jj = xw + tid;
      if (jj < DDET){
        float s = red[tid] + red[64+tid] + red[128+tid] + red[192+tid];
        h1[y*DDET + jj] = s;
      }
    }
  }
}

// ---------------- backprojection: writes NHWC8 ch5 bf16 hi/lo ----------------
__global__ __launch_bounds__(256) void backproj_kernel(
    const float* __restrict__ h1, const float* __restrict__ trig,
    unsigned short* __restrict__ hi8, unsigned short* __restrict__ lo8){
  __shared__ float sh[AANG*28];
  __shared__ int   sbase[AANG];
  __shared__ float strig[2*AANG];
  int tid = threadIdx.x;
  int x0 = (blockIdx.x & 31) * 16, y0 = (blockIdx.x >> 5) * 16;
  if (tid < 2*AANG) strig[tid] = trig[tid];
  __syncthreads();
  if (tid < AANG){
    float ca = strig[tid], sa = strig[AANG+tid];
    float Xa = (float)x0 - 255.5f, Xb = Xa + 15.f;
    float Ya = (float)y0 - 255.5f, Yb = Ya + 15.f;
    float s00 = Xa*ca + Ya*sa, s01 = Xb*ca + Ya*sa;
    float s10 = Xa*ca + Yb*sa, s11 = Xb*ca + Yb*sa;
    float mn = fminf(fminf(s00,s01), fminf(s10,s11)) + 364.0f;
    sbase[tid] = (int)floorf(mn) - 2;
  }
  __syncthreads();
  for (int s = tid; s < AANG*28; s += 256){
    int a = s / 28, j = s - a*28;
    int idx = sbase[a] + j;
    sh[s] = (idx >= 0 && idx < DDET) ? h1[a*DDET + idx] : 0.f;
  }
  __syncthreads();
  int x = x0 + (tid & 15), y = y0 + (tid >> 4);
  float X = (float)x - 255.5f, Y = (float)y - 255.5f;
  float acc = 0.f;
  #pragma unroll 6
  for (int a=0;a<AANG;a++){
    float sidx = fmaf(X, strig[a], fmaf(Y, strig[AANG+a], 364.0f));
    float ff = floorf(sidx);
    int k = (int)ff - sbase[a];
    float fi = sidx - ff;
    float v0 = sh[a*28+k], v1 = sh[a*28+k+1];
    acc += v0 + fi*(v1-v0);
  }
  unsigned p = pack_hilo(acc);
  size_t p8 = ((size_t)(y*SS + x))*8 + 5;
  hi8[p8] = (unsigned short)(p >> 16);
  lo8[p8] = (unsigned short)(p & 0xffffu);
}

// ---------------- primal conv1 (6->32): implicit-GEMM MFMA on NHWC8 input ----------------
__global__ __launch_bounds__(256) void prim1_mfma(
    const unsigned short* __restrict__ hi8, const unsigned short* __restrict__ lo8,  // [512][512][8]
    const unsigned short* __restrict__ Bimg1,   // this layer: [3][2][2][64][8]
    const float* __restrict__ bias, const float* __restrict__ prelu,
    unsigned short* __restrict__ outHi, unsigned short* __restrict__ outLo)
{
  __shared__ unsigned int tr[4][64][33];
  int b = blockIdx.x;                 // 0..1023
  int by = b >> 1, half = b & 1;
  int y = ((by & 7) << 6) | (by >> 3);   // XCD row swizzle
  int wv = (int)threadIdx.x >> 6;
  int lane = (int)threadIdx.x & 63;
  int xw = half*256 + wv*64;
  int lm = lane & 15, lq = lane >> 4;
  f32x4 acc[4][2];
  #pragma unroll
  for (int s=0;s<4;s++){ acc[s][0] = (f32x4)0.f; acc[s][1] = (f32x4)0.f; }
  bool fast = (y>0) && (y<511) && (xw!=0) && (xw!=448);
  const short8* Bf = (const short8*)Bimg1;
  #pragma unroll
  for (int g=0; g<3; g++){
    const short8* bp8 = Bf + g*256 + lane;
    short8 bh0 = bp8[0];
    short8 bl0 = bp8[64];
    short8 bh1 = bp8[128];
    short8 bl1 = bp8[192];
    int t = g*4 + lq; if (t > 8) t = 8;
    int dy = (t >= 6) ? 1 : ((t >= 3) ? 0 : -1);
    int dx = t - (dy+1)*3 - 1;
    int row = y + dy;
    #pragma unroll
    for (int s=0; s<4; s++){
      short8 ah, al;
      int px = xw + s*16 + lm + dx;
      if (fast){
        size_t off = ((size_t)row*SS + px)*8;
        ah = *(const short8*)(hi8 + off);
        al = *(const short8*)(lo8 + off);
      } else {
        bool ok = ((unsigned)row < 512u) && ((unsigned)px < 512u);
        size_t off = ok ? ((size_t)row*SS + px)*8 : 0;
        ah = ok ? *(const short8*)(hi8 + off) : (short8)0;
        al = ok ? *(const short8*)(lo8 + off) : (short8)0;
      }
      acc[s][0] = __builtin_amdgcn_mfma_f32_16x16x32_bf16(ah, bh0, acc[s][0], 0,0,0);
      acc[s][1] = __builtin_amdgcn_mfma_f32_16x16x32_bf16(ah, bh1, acc[s][1], 0,0,0);
      acc[s][0] = __builtin_amdgcn_mfma_f32_16x16x32_bf16(al, bh0, acc[s][0], 0,0,0);
      acc[s][1] = __builtin_amdgcn_mfma_f32_16x16x32_bf16(al, bh1, acc[s][1], 0,0,0);
      acc[s][0] = __builtin_amdgcn_mfma_f32_16x16x32_bf16(ah, bl0, acc[s][0], 0,0,0);
      acc[s][1] = __builtin_amdgcn_mfma_f32_16x16x32_bf16(ah, bl1, acc[s][1], 0,0,0);
    }
  }
  // epilogue: bias + prelu + pack hi/lo into LDS [px][ch], NHWC32 stores
  float aa = *prelu;
  #pragma unroll
  for (int s=0;s<4;s++){
    #pragma unroll
    for (int n=0;n<2;n++){
      int o = n*16 + lm;
      float bv = bias[o];
      f32x4 v = acc[s][n];
      v.x+=bv; v.y+=bv; v.z+=bv; v.w+=bv;
      v.x=(v.x>=0.f)?v.x:aa*v.x; v.y=(v.y>=0.f)?v.y:aa*v.y;
      v.z=(v.z>=0.f)?v.z:aa*v.z; v.w=(v.w>=0.f)?v.w:aa*v.w;
      #pragma unroll
      for (int r=0;r<4;r++)
        tr[wv][s*16 + lq*4 + r][o] = pack_hilo(v[r]);
    }
  }
  __syncthreads();
  int c8 = lane & 3;
  int pxl = lane >> 2;
  #pragma unroll
  for (int k=0;k<4;k++){
    int px = pxl + k*16;
    short8 vh, vl;
    #pragma unroll
    for (int j=0;j<8;j++){
      unsigned p = tr[wv][px][c8*8 + j];
      vh[j] = (short)(p >> 16);
      vl[j] = (short)(p & 0xffffu);
    }
    size_t base = ((size_t)(y*SS + xw + px))*32 + c8*8;
    *(short8*)(outHi + base) = vh;
    *(short8*)(outLo + base) = vl;
  }
}

// ---------------- primal conv2 (32->32): implicit-GEMM MFMA bf16 hi/lo ----------------
__global__ __launch_bounds__(256) void conv_mfma32(
    const unsigned short* __restrict__ hiB, const unsigned short* __restrict__ loB,
    const unsigned short* __restrict__ Bimg,   // this layer: [9][2][2][64][8]
    const float* __restrict__ bias, const float* __restrict__ prelu,
    unsigned short* __restrict__ outHi, unsigned short* __restrict__ outLo)
{
  __shared__ unsigned int tr[4][64][33];
  int b = blockIdx.x;                 // 0..1023
  int by = b >> 1, half = b & 1;
  int y = ((by & 7) << 6) | (by >> 3);   // XCD row swizzle
  int wv = (int)threadIdx.x >> 6;
  int lane = (int)threadIdx.x & 63;
  int xw = half*256 + wv*64;
  int lm = lane & 15, lq = lane >> 4;
  int laneoff = lm*32 + lq*8;
  f32x4 acc[4][2];
  #pragma unroll
  for (int s=0;s<4;s++){ acc[s][0] = (f32x4)0.f; acc[s][1] = (f32x4)0.f; }
  bool fastx = (xw != 0) && (xw != 448);
  const short8* Bf = (const short8*)Bimg;
  #pragma unroll
  for (int dy=-1; dy<=1; dy++){
    int yy = y + dy;
    if ((unsigned)yy >= 512u) continue;
    const unsigned short* rh = hiB + (size_t)yy*512*32;
    const unsigned short* rl = loB + (size_t)yy*512*32;
    #pragma unroll
    for (int dx=-1; dx<=1; dx++){
      int tap = (dy+1)*3 + (dx+1);
      const short8* bp8 = Bf + tap*256 + lane;
      short8 bh0 = bp8[0];     // n=0 hi
      short8 bl0 = bp8[64];    // n=0 lo
      short8 bh1 = bp8[128];   // n=1 hi
      short8 bl1 = bp8[192];   // n=1 lo
      int xoff = (xw + dx)*32 + laneoff;
      #pragma unroll
      for (int s=0; s<4; s++){
        short8 ah, al;
        const unsigned short* ph = rh + xoff + s*512;
        const unsigned short* pl = rl + xoff + s*512;
        if (fastx){
          ah = *(const short8*)ph;
          al = *(const short8*)pl;
        } else {
          int x = xw + s*16 + lm + dx;
          bool ok = ((unsigned)x < 512u);
          ah = ok ? *(const short8*)ph : (short8)0;
          al = ok ? *(const short8*)pl : (short8)0;
        }
        acc[s][0] = __builtin_amdgcn_mfma_f32_16x16x32_bf16(ah, bh0, acc[s][0], 0,0,0);
        acc[s][1] = __builtin_amdgcn_mfma_f32_16x16x32_bf16(ah, bh1, acc[s][1], 0,0,0);
        acc[s][0] = __builtin_amdgcn_mfma_f32_16x16x32_bf16(al, bh0, acc[s][0], 0,0,0);
        acc[s][1] = __builtin_amdgcn_mfma_f32_16x16x32_bf16(al, bh1, acc[s][1], 0,0,0);
        acc[s][0] = __builtin_amdgcn_mfma_f32_16x16x32_bf16(ah, bl0, acc[s][0], 0,0,0);
        acc[s][1] = __builtin_amdgcn_mfma_f32_16x16x32_bf16(ah, bl1, acc[s][1], 0,0,0);
      }
    }
  }
  // epilogue: bias + prelu + pack hi/lo into LDS [px][ch]
  float aa = *prelu;
  #pragma unroll
  for (int s=0;s<4;s++){
    #pragma unroll
    for (int n=0;n<2;n++){
      int o = n*16 + lm;
      float bv = bias[o];
      f32x4 v = acc[s][n];
      v.x+=bv; v.y+=bv; v.z+=bv; v.w+=bv;
      v.x=(v.x>=0.f)?v.x:aa*v.x; v.y=(v.y>=0.f)?v.y:aa*v.y;
      v.z=(v.z>=0.f)?v.z:aa*v.z; v.w=(v.w>=0.f)?v.w:aa*v.w;
      #pragma unroll
      for (int r=0;r<4;r++)
        tr[wv][s*16 + lq*4 + r][o] = pack_hilo(v[r]);
    }
  }
  __syncthreads();
  // read channel-contiguous, split, coalesced NHWC stores
  int c8 = lane & 3;             // 8-channel chunk
  int pxl = lane >> 2;           // 0..15
  #pragma unroll
  for (int k=0;k<4;k++){
    int px = pxl + k*16;
    short8 vh, vl;
    #pragma unroll
    for (int j=0;j<8;j++){
      unsigned p = tr[wv][px][c8*8 + j];
      vh[j] = (short)(p >> 16);
      vl[j] = (short)(p & 0xffffu);
    }
    size_t base = ((size_t)(y*SS + xw + px))*32 + c8*8;
    *(short8*)(outHi + base) = vh;
    *(short8*)(outLo + base) = vl;
  }
}

// ---------------- primal conv3 (32->5): implicit-GEMM MFMA, N=16 (5 real) ----------------
__global__ __launch_bounds__(256) void duo_mfma(
    const unsigned short* __restrict__ hiB, const unsigned short* __restrict__ loB,
    const unsigned short* __restrict__ Bimg3,   // this layer: [9][2][64][8]
    const float* __restrict__ bias,
    float* __restrict__ f,
    float* __restrict__ fout, float* __restrict__ tout,
    unsigned short* __restrict__ hi8, unsigned short* __restrict__ lo8)
{
  __shared__ unsigned int t8[4][64][6];
  int b = blockIdx.x;                 // 0..1023
  int by = b >> 1, half = b & 1;
  int y = ((by & 7) << 6) | (by >> 3);   // XCD row swizzle
  int wv = (int)threadIdx.x >> 6;
  int lane = (int)threadIdx.x & 63;
  int xw = half*256 + wv*64;
  int lm = lane & 15, lq = lane >> 4;
  int laneoff = lm*32 + lq*8;
  f32x4 acc[4];
  #pragma unroll
  for (int s=0;s<4;s++) acc[s] = (f32x4)0.f;
  bool fastx = (xw != 0) && (xw != 448);
  const short8* Bf = (const short8*)Bimg3;
  #pragma unroll
  for (int dy=-1; dy<=1; dy++){
    int yy = y + dy;
    if ((unsigned)yy >= 512u) continue;
    const unsigned short* rh = hiB + (size_t)yy*512*32;
    const unsigned short* rl = loB + (size_t)yy*512*32;
    #pragma unroll
    for (int dx=-1; dx<=1; dx++){
      int tap = (dy+1)*3 + (dx+1);
      const short8* bp8 = Bf + tap*128 + lane;
      short8 bh = bp8[0];
      short8 bl = bp8[64];
      int xoff = (xw + dx)*32 + laneoff;
      #pragma unroll
      for (int s=0; s<4; s++){
        short8 ah, al;
        const unsigned short* ph = rh + xoff + s*512;
        const unsigned short* pl = rl + xoff + s*512;
        if (fastx){
          ah = *(const short8*)ph;
          al = *(const short8*)pl;
        } else {
          int x = xw + s*16 + lm + dx;
          bool ok = ((unsigned)x < 512u);
          ah = ok ? *(const short8*)ph : (short8)0;
          al = ok ? *(const short8*)pl : (short8)0;
        }
        acc[s] = __builtin_amdgcn_mfma_f32_16x16x32_bf16(ah, bh, acc[s], 0,0,0);
        acc[s] = __builtin_amdgcn_mfma_f32_16x16x32_bf16(al, bh, acc[s], 0,0,0);
        acc[s] = __builtin_amdgcn_mfma_f32_16x16x32_bf16(ah, bl, acc[s], 0,0,0);
      }
    }
  }
  // epilogue: f += conv3 + bias on lanes lm<5; imgT transpose (lm==1); output rep (lm==0)
  if (lm < 5){
    float bv = bias[lm];
    #pragma unroll
    for (int s=0;s<4;s++){
      int px0 = xw + s*16 + lq*4;
      float* op = f + (size_t)lm*NPIX + y*SS + px0;
      f32x4 old = *(const f32x4*)op;
      f32x4 v = acc[s];
      v.x += old.x + bv; v.y += old.y + bv;
      v.z += old.z + bv; v.w += old.w + bv;
      *(f32x4*)op = v;
      #pragma unroll
      for (int r=0;r<4;r++)
        t8[wv][s*16 + lq*4 + r][lm] = pack_hilo(v[r]);
      if (lm == 1){
        tout[(px0  )*SS + y] = v.x;
        tout[(px0+1)*SS + y] = v.y;
        tout[(px0+2)*SS + y] = v.z;
        tout[(px0+3)*SS + y] = v.w;
      }
      if (lm == 0 && fout){
        float* q = fout + y*SS + px0;
        *(f32x4*)q = v;
        *(f32x4*)(q + NPIX) = v;
        *(f32x4*)(q + 2*NPIX) = v;
      }
    }
  }
  __syncthreads();
  // readout: lane = px; write NHWC8 ch0-4 (8B + 2B stores, hi and lo)
  {
    unsigned c0 = t8[wv][lane][0], c1 = t8[wv][lane][1], c2 = t8[wv][lane][2];
    unsigned c3 = t8[wv][lane][3], c4 = t8[wv][lane][4];
    size_t base = ((size_t)(y*SS + xw + lane))*8;
    short4v vh; vh[0]=(short)(c0>>16); vh[1]=(short)(c1>>16); vh[2]=(short)(c2>>16); vh[3]=(short)(c3>>16);
    short4v vl; vl[0]=(short)(c0&0xffffu); vl[1]=(short)(c1&0xffffu); vl[2]=(short)(c2&0xffffu); vl[3]=(short)(c3&0xffffu);
    *(short4v*)(hi8 + base) = vh;
    *(short4v*)(lo8 + base) = vl;
    hi8[base+4] = (unsigned short)(c4>>16);
    lo8[base+4] = (unsigned short)(c4&0xffffu);
  }
}

extern "C" void kernel_launch(void* const* d_in, const int* in_sizes, int n_in,
                              void* d_out, int out_size, void* d_ws, size_t ws_size,
                              hipStream_t stream){
  const float* g     = (const float*)d_in[2];
  const float* theta = (const float*)d_in[3];
  const float* dw1 = (const float*)d_in[5];
  const float* db1 = (const float*)d_in[6];
  const float* da1 = (const float*)d_in[7];
  const float* dw2 = (const float*)d_in[8];
  const float* db2 = (const float*)d_in[9];
  const float* da2 = (const float*)d_in[10];
  const float* dw3 = (const float*)d_in[11];
  const float* db3 = (const float*)d_in[12];
  const float* pw1 = (const float*)d_in[13];
  const float* pb1 = (const float*)d_in[14];
  const float* pa1 = (const float*)d_in[15];
  const float* pw2 = (const float*)d_in[16];
  const float* pb2 = (const float*)d_in[17];
  const float* pa2 = (const float*)d_in[18];
  const float* pw3 = (const float*)d_in[19];
  const float* pb3 = (const float*)d_in[20];

  float* ws     = (float*)d_ws;
  float* trig   = ws;                    // 128
  float* taps   = ws + 128;              // 1457 -> ends 1585
  int*   barcnt = (int*)(ws + 1600);     // 10 ints
  float* h      = ws + 2048;             // 5*NSIN
  float* opf    = h + 5*NSIN;            // NSIN (unused, keeps layout)
  float* gcopy  = opf + NSIN;            // NSIN (unused, keeps layout)
  float* h1     = gcopy + NSIN;          // NSIN
  float* f      = h1 + NSIN;             // 5*NPIX
  float* bp     = f + 5*NPIX;            // NPIX (unused, keeps layout)
  float* imgT   = bp + NPIX;             // NPIX
  float* dualT1 = imgT + NPIX;           // 32*NSIN slot -> dual2Hi
  float* dualT2 = dualT1 + 32*NSIN;      // 32*NSIN slot -> dual2Lo
  float* primT2slot = dualT2 + 32*NSIN;  // 32*NPIX floats of space
  unsigned short* primHi = (unsigned short*)primT2slot;          // 32*NPIX ushorts
  unsigned short* primLo = primHi + (size_t)32*NPIX;             // 32*NPIX ushorts
  unsigned short* nhwcHi = (unsigned short*)(primT2slot + 32*NPIX);  // 32*NPIX ushorts
  unsigned short* nhwcLo = nhwcHi + (size_t)32*NPIX;             // 32*NPIX ushorts
  float* wsp   = (float*)(nhwcLo + (size_t)32*NPIX);
  unsigned short* Bimg  = (unsigned short*)(wsp + 158400);       // 184320 ushorts
  unsigned short* Bimg2 = Bimg + 184320;                         // 184320 ushorts
  unsigned short* Bimg3 = Bimg2 + 184320;                        // 92160 ushorts
  unsigned short* Bimg1 = Bimg3 + 92160;                         // 61440 ushorts
  unsigned short* Bimg1d = Bimg1 + 61440;                        // 61440 ushorts
  unsigned short* Bimg3d = Bimg1d + 61440;                       // 92160 ushorts
  // dual NHWC32 hi/lo: 62 rows x DRS x 32ch + 64-ushort zero prefix/suffix
  const size_t DUALSZ = (size_t)64 + (size_t)62*DRS*32 + 64;
  unsigned short* dualHiRaw = Bimg3d + 92160;
  unsigned short* dualLoRaw = dualHiRaw + DUALSZ;
  unsigned short* dualHi = dualHiRaw + 64;
  unsigned short* dualLo = dualLoRaw + 64;
  // dual conv2 NHWC32 output in recycled dualT1/dualT2 slots
  unsigned short* dual2HiRaw = (unsigned short*)dualT1;
  unsigned short* dual2LoRaw = (unsigned short*)dualT2;
  unsigned short* dual2Hi = dual2HiRaw + 64;
  unsigned short* dual2Lo = dual2LoRaw + 64;
  // primal NHWC8 input image [512][512][8] bf16 hi/lo
  unsigned short* nh8Hi = dualLoRaw + DUALSZ;
  unsigned short* nh8Lo = nh8Hi + (size_t)NPIX*8;
  // sinogram NHWC8 input image [62][DRS][8] bf16 hi/lo + 64-ushort prefix/suffix
  const size_t S8SZ = (size_t)64 + (size_t)62*DRS*8 + 64;
  unsigned short* s8HiRaw = nh8Lo + (size_t)NPIX*8;
  unsigned short* s8LoRaw = s8HiRaw + S8SZ;
  unsigned short* s8Hi = s8HiRaw + 64;
  unsigned short* s8Lo = s8LoRaw + 64;

  hipMemsetAsync(barcnt, 0, 10*sizeof(int), stream);
  hipMemsetAsync(h, 0, (size_t)(5*NSIN)*sizeof(float), stream);
  hipMemsetAsync(f, 0, (size_t)(7*NPIX)*sizeof(float), stream);   // f, bp, imgT
  hipMemsetAsync(dualHiRaw, 0, 2*DUALSZ*sizeof(unsigned short), stream);  // zero pads once
  hipMemsetAsync(dual2HiRaw, 0, DUALSZ*sizeof(unsigned short), stream);   // zero pads once
  hipMemsetAsync(dual2LoRaw, 0, DUALSZ*sizeof(unsigned short), stream);   // zero pads once
  hipMemsetAsync(nh8Hi, 0, (size_t)2*NPIX*8*sizeof(unsigned short), stream); // zero once
  hipMemsetAsync(s8HiRaw, 0, 2*S8SZ*sizeof(unsigned short), stream); // zero once
  trig_kernel<<<1,64,0,stream>>>(theta, trig);
  taps_kernel<<<NTAPS,256,0,stream>>>(taps);
  prep_bimg<<<(92160+255)/256,256,0,stream>>>(pw2, Bimg);
  prep_bimg<<<(92160+255)/256,256,0,stream>>>(dw2, Bimg2);
  prep_bimg3<<<(46080+255)/256,256,0,stream>>>(pw3, Bimg3);
  prep_bimg3<<<(46080+255)/256,256,0,stream>>>(dw3, Bimg3d);
  prep_bimg1c<<<(30720+255)/256,256,0,stream>>>(pw1, Bimg1, 6);
  prep_bimg1c<<<(30720+255)/256,256,0,stream>>>(dw1, Bimg1d, 7);
  g_to_nhwc8<<<(NSIN+255)/256,256,0,stream>>>(g, s8Hi, s8Lo);

  for (int i=0;i<10;i++){
    radon_fwd_kernel<<<(NSIN+3)/4,256,0,stream>>>(f + NPIX, imgT, trig, s8Hi, s8Lo);
    // fused dual block: conv1 -> conv2 -> conv3 -> ramp filter (3 grid barriers)
    dual_chain<<<720,256,0,stream>>>(s8Hi, s8Lo, dualHi, dualLo, dual2Hi, dual2Lo,
                                     Bimg1d+(size_t)i*6144, Bimg2+(size_t)i*18432,
                                     Bimg3d+(size_t)i*9216,
                                     db1+(size_t)i*32, da1+i, db2+(size_t)i*32, da2+i,
                                     db3+(size_t)i*5, h, h1, taps, barcnt + i);
    backproj_kernel<<<NPIX/256,256,0,stream>>>(h1, trig, nh8Hi, nh8Lo);
    // primal block: NHWC8 [f(5)|bp|0|0] -> conv1 -> conv2 -> conv3
    prim1_mfma<<<1024,256,0,stream>>>(nh8Hi, nh8Lo, Bimg1+(size_t)i*6144,
                                      pb1+(size_t)i*32, pa1+i, nhwcHi, nhwcLo);
    conv_mfma32<<<1024,256,0,stream>>>(nhwcHi, nhwcLo, Bimg+(size_t)i*18432, pb2+(size_t)i*32, pa2+i, primHi, primLo);
    duo_mfma<<<1024,256,0,stream>>>(primHi, primLo, Bimg3+(size_t)i*9216, pb3+(size_t)i*5, f,
                                    (i==9) ? (float*)d_out : nullptr, imgT, nh8Hi, nh8Lo);
  }
}

// Round 9
// 1793.334 us; speedup vs baseline: 3.7094x; 3.7094x over previous
//
#include <hip/hip_runtime.h>
#include <math.h>

#define SS 512
#define AANG 60
#define DDET 729
#define NPIX (SS*SS)        // 262144
#define NSIN (AANG*DDET)    // 43740
#define NTAPS 1457
#define DRS 768             // dual NHWC padded row stride

typedef float v4u __attribute__((ext_vector_type(4), aligned(4)));
typedef float v2u __attribute__((ext_vector_type(2), aligned(8)));
typedef short short8 __attribute__((ext_vector_type(8)));
typedef short short4v __attribute__((ext_vector_type(4)));
typedef float f32x4 __attribute__((ext_vector_type(4)));

// round-to-nearest-even fp32 -> bf16 bits
__device__ inline unsigned short f2bf(float x){
  unsigned u = __float_as_uint(x);
  return (unsigned short)((u + 0x7fffu + ((u >> 16) & 1u)) >> 16);
}

// ---------------- trig table ----------------
__global__ void trig_kernel(const float* __restrict__ theta, float* __restrict__ trig){
  int a = threadIdx.x;
  if (a < AANG){ trig[a] = cosf(theta[a]); trig[AANG+a] = sinf(theta[a]); }
}

// ---------------- ramp-filter taps ----------------
__global__ void taps_kernel(float* __restrict__ taps){
  __shared__ double red[256];
  int m  = blockIdx.x;
  int mm = m - 728;
  double s = 0.0;
  for (int k = 1 + (int)threadIdx.x; k <= 1023; k += 256){
    int phase = (k*mm) & 2047;
    s += (double)k * cos((double)phase * (M_PI/1024.0));
  }
  red[threadIdx.x] = s;
  __syncthreads();
  for (int off=128; off; off>>=1){
    if ((int)threadIdx.x < off) red[threadIdx.x] += red[threadIdx.x+off];
    __syncthreads();
  }
  if (threadIdx.x==0){
    double x = (red[0]*(1.0/512.0) + ((mm & 1) ? -1.0 : 1.0)) / 2048.0;
    taps[m] = (float)(x * (M_PI/120.0));
  }
}

// -------- MFMA B-fragment image: [L][tap=9][n=2][prod=2][lane=64][8] bf16 --------
// works for any [L][32][32][3][3] weight tensor (pw2 and dw2)
__global__ void prep_bimg(const float* __restrict__ w, unsigned short* __restrict__ B){
  int idx = blockIdx.x*256 + (int)threadIdx.x;
  if (idx >= 10*9*2*64*8) return;
  int j    =  idx        & 7;
  int lane = (idx >> 3)  & 63;
  int n    = (idx >> 9)  & 1;
  int r    =  idx >> 10;          // l*9 + tap
  int tap = r % 9, l = r / 9;
  int c = (lane >> 4)*8 + j;      // k = channel
  int o = n*16 + (lane & 15);     // output channel
  float x = w[(((size_t)(l*32+o)*32 + c)*9) + tap];
  unsigned short hb = f2bf(x);
  float hf = __uint_as_float((unsigned)hb << 16);
  unsigned short lb = f2bf(x - hf);
  size_t d = (size_t)l*18432 + (size_t)tap*2048 + n*1024 + lane*8 + j;
  B[d]       = hb;
  B[d + 512] = lb;
}

// -------- MFMA B-fragment image for [L][5][32][3][3]: [L][tap=9][prod=2][lane=64][8] --------
__global__ void prep_bimg3(const float* __restrict__ w, unsigned short* __restrict__ B){
  int idx = blockIdx.x*256 + (int)threadIdx.x;
  if (idx >= 10*9*64*8) return;
  int j    =  idx       & 7;
  int lane = (idx >> 3) & 63;
  int r    =  idx >> 9;           // l*9 + tap
  int tap = r % 9, l = r / 9;
  int c = (lane >> 4)*8 + j;      // k = channel
  int o = lane & 15;              // output channel (5 real)
  float x = (o < 5) ? w[(((size_t)(l*5+o)*32 + c)*9) + tap] : 0.f;
  unsigned short hb = f2bf(x);
  float hf = __uint_as_float((unsigned)hb << 16);
  unsigned short lb = f2bf(x - hf);
  size_t d = (size_t)l*9216 + (size_t)tap*1024 + lane*8 + j;
  B[d]       = hb;
  B[d + 512] = lb;
}

// -------- MFMA B-fragment image for NHWC8 conv1 weights [L][32][Cin][3][3] --------
// layout [L][g=3][n=2][prod=2][64][8]; k = tap_local*8 + ch; t = g*4+tap_local
__global__ void prep_bimg1c(const float* __restrict__ w, unsigned short* __restrict__ B, int Cin){
  int idx = blockIdx.x*256 + (int)threadIdx.x;
  if (idx >= 10*3*2*64*8) return;
  int j    =  idx       & 7;
  int lane = (idx >> 3) & 63;
  int n    = (idx >> 9) & 1;
  int r    =  idx >> 10;          // l*3 + g
  int g = r % 3, l = r / 3;
  int t = g*4 + (lane >> 4);
  int o = n*16 + (lane & 15);
  float x = (t < 9 && j < Cin) ? w[(((size_t)(l*32+o)*Cin + j)*9) + t] : 0.f;
  unsigned short hb = f2bf(x);
  float hf = __uint_as_float((unsigned)hb << 16);
  unsigned short lb = f2bf(x - hf);
  size_t d = (size_t)l*6144 + (size_t)g*2048 + n*1024 + lane*8 + j;
  B[d]       = hb;
  B[d + 512] = lb;
}

// ---------------- g -> sinogram NHWC8 ch6 (once) ----------------
__global__ void g_to_nhwc8(const float* __restrict__ g,
                           unsigned short* __restrict__ s8hi, unsigned short* __restrict__ s8lo){
  int idx = blockIdx.x*256 + (int)threadIdx.x;
  if (idx >= NSIN) return;
  int a = idx / DDET, d = idx - a*DDET;
  float x = g[idx];
  unsigned short hb = f2bf(x);
  float hf = __uint_as_float((unsigned)hb << 16);
  unsigned short lb = f2bf(x - hf);
  size_t p8 = ((size_t)(a+1)*DRS + d)*8 + 6;
  s8hi[p8] = hb;
  s8lo[p8] = lb;
}

// ---------------- radon forward: rcp-hoisted clip; writes NHWC8sin ch5 ----------------
__device__ inline void clipr(float al, float ial, float be, float lo, float hi,
                             float& A, float& B, bool& empty){
  if (fabsf(al) < 1e-7f){ if (be < lo || be > hi) empty = true; return; }
  float t0 = (lo - be)*ial, t1 = (hi - be)*ial;
  float mn = fminf(t0,t1), mx = fmaxf(t0,t1);
  A = fmaxf(A, mn); B = fminf(B, mx);
}

__device__ inline float samp_guard(const float* __restrict__ base, float aR, float bR,
                                   float aC, float bC, int t){
  float tp = (float)t - 255.5f;
  float R = fmaf(aR, tp, bR);
  float C = fmaf(aC, tp, bC);
  float rf = floorf(R), cf = floorf(C);
  int r0 = (int)rf, c0 = (int)cf;
  int r1 = r0+1,    c1 = c0+1;
  float fr = R - rf, fc = C - cf;
  bool r0ok = (r0>=0 && r0<SS), r1ok = (r1>=0 && r1<SS);
  bool c0ok = (c0>=0 && c0<SS), c1ok = (c1>=0 && c1<SS);
  float v00 = (r0ok && c0ok) ? base[r0*SS+c0] : 0.f;
  float v01 = (r0ok && c1ok) ? base[r0*SS+c1] : 0.f;
  float v10 = (r1ok && c0ok) ? base[r1*SS+c0] : 0.f;
  float v11 = (r1ok && c1ok) ? base[r1*SS+c1] : 0.f;
  return (1.f-fr)*((1.f-fc)*v00 + fc*v01) + fr*((1.f-fc)*v10 + fc*v11);
}

__global__ __launch_bounds__(256) void radon_fwd_kernel(
    const float* __restrict__ img, const float* __restrict__ imgT,
    const float* __restrict__ trig,
    unsigned short* __restrict__ s8hi, unsigned short* __restrict__ s8lo){
  int gid  = blockIdx.x*4 + ((int)threadIdx.x >> 6);
  int lane = (int)threadIdx.x & 63;
  if (gid >= NSIN) return;
  int a = gid / DDET;
  int d = gid - a*DDET;
  float ca = trig[a], sa = trig[AANG+a];
  float sd = (float)d - 364.0f;
  float Rc = fmaf(sd, sa, 255.5f);
  float Cc = fmaf(sd, ca, 255.5f);
  float aR = ca, bR = Rc, aC = -sa, bC = Cc;
  const float* base = img;
  if (fabsf(ca) > fabsf(sa)){
    base = imgT;
    float tmp;
    tmp=aR; aR=aC; aC=tmp;
    tmp=bR; bR=bC; bC=tmp;
  }
  float iaR = __builtin_amdgcn_rcpf(aR);
  float iaC = __builtin_amdgcn_rcpf(aC);
  float tiA = -255.5f, tiB = 255.5f;  bool iE=false;
  float teA = -255.5f, teB = 255.5f;  bool eE=false;
  clipr(aR,iaR,bR, 0.001f, 510.999f, tiA,tiB,iE);
  clipr(aC,iaC,bC, 0.001f, 510.999f, tiA,tiB,iE);
  clipr(aR,iaR,bR, -0.999f, 511.999f, teA,teB,eE);
  clipr(aC,iaC,bC, -0.999f, 511.999f, teA,teB,eE);
  float acc = 0.f;
  if (!eE && teA <= teB){
    int eA = max(0,   (int)floorf(teA+255.5f) - 1);
    int eB = min(511, (int)ceilf (teB+255.5f) + 1);
    int iA = (int)ceilf (tiA+255.5f) + 1;
    int iB = (int)floorf(tiB+255.5f) - 1;
    iA = max(iA, eA); iB = min(iB, eB);
    if (iE || iA > iB){
      for (int t = eA+lane; t <= eB; t += 64) acc += samp_guard(base,aR,bR,aC,bC,t);
    } else {
      for (int t = eA+lane;   t <  iA; t += 64) acc += samp_guard(base,aR,bR,aC,bC,t);
      for (int t = iB+1+lane; t <= eB; t += 64) acc += samp_guard(base,aR,bR,aC,bC,t);
      for (int t = iA+lane;   t <= iB; t += 64){
        float tp = (float)t - 255.5f;
        float R = fmaf(aR, tp, bR);
        float C = fmaf(aC, tp, bC);
        int r0 = (int)R, c0 = (int)C;
        float fr = R - (float)r0, fc = C - (float)c0;
        const float* p = base + r0*SS + c0;
        float v00 = p[0], v01 = p[1], v10 = p[SS], v11 = p[SS+1];
        float top = v00 + fc*(v01-v00);
        float bot = v10 + fc*(v11-v10);
        acc += top + fr*(bot-top);
      }
    }
  }
  for (int off=32; off; off>>=1) acc += __shfl_down(acc, off);
  if (lane==0){
    unsigned short hb = f2bf(acc);
    float hf = __uint_as_float((unsigned)hb << 16);
    unsigned short lb = f2bf(acc - hf);
    size_t p8 = ((size_t)(a+1)*DRS + d)*8 + 5;
    s8hi[p8] = hb;
    s8lo[p8] = lb;
  }
}

// ---------------- ramp filter: 4-way k-split, 64 outputs/block ----------------
__global__ __launch_bounds__(256) void filter_kernel2(
    const float* __restrict__ h0, const float* __restrict__ taps,
    float* __restrict__ h1){
  __shared__ float red[256];
  int a  = blockIdx.x / 12;
  int jb = blockIdx.x - a*12;
  int jl = (int)threadIdx.x & 63;
  int kq = (int)threadIdx.x >> 6;
  int j  = jb*64 + jl;
  float acc = 0.f;
  if (j < DDET){
    const float* row = h0 + a*DDET;
    const float* tp  = taps + 728 + j;
    int k0 = kq*183;
    int k1 = min(k0+183, DDET);
    for (int k=k0;k<k1;k++) acc = fmaf(row[k], tp[-k], acc);
  }
  red[threadIdx.x] = acc;
  __syncthreads();
  if ((int)threadIdx.x < 64 && j < DDET){
    float s = red[jl] + red[64+jl] + red[128+jl] + red[192+jl];
    h1[a*DDET + j] = s;
  }
}

// ---------------- backprojection: writes NHWC8 ch5 bf16 hi/lo ----------------
__global__ __launch_bounds__(256) void backproj_kernel(
    const float* __restrict__ h1, const float* __restrict__ trig,
    unsigned short* __restrict__ hi8, unsigned short* __restrict__ lo8){
  __shared__ float sh[AANG*28];
  __shared__ int   sbase[AANG];
  __shared__ float strig[2*AANG];
  int tid = threadIdx.x;
  int x0 = (blockIdx.x & 31) * 16, y0 = (blockIdx.x >> 5) * 16;
  if (tid < 2*AANG) strig[tid] = trig[tid];
  __syncthreads();
  if (tid < AANG){
    float ca = strig[tid], sa = strig[AANG+tid];
    float Xa = (float)x0 - 255.5f, Xb = Xa + 15.f;
    float Ya = (float)y0 - 255.5f, Yb = Ya + 15.f;
    float s00 = Xa*ca + Ya*sa, s01 = Xb*ca + Ya*sa;
    float s10 = Xa*ca + Yb*sa, s11 = Xb*ca + Yb*sa;
    float mn = fminf(fminf(s00,s01), fminf(s10,s11)) + 364.0f;
    sbase[tid] = (int)floorf(mn) - 2;
  }
  __syncthreads();
  for (int s = tid; s < AANG*28; s += 256){
    int a = s / 28, j = s - a*28;
    int idx = sbase[a] + j;
    sh[s] = (idx >= 0 && idx < DDET) ? h1[a*DDET + idx] : 0.f;
  }
  __syncthreads();
  int x = x0 + (tid & 15), y = y0 + (tid >> 4);
  float X = (float)x - 255.5f, Y = (float)y - 255.5f;
  float acc = 0.f;
  #pragma unroll 6
  for (int a=0;a<AANG;a++){
    float sidx = fmaf(X, strig[a], fmaf(Y, strig[AANG+a], 364.0f));
    float ff = floorf(sidx);
    int k = (int)ff - sbase[a];
    float fi = sidx - ff;
    float v0 = sh[a*28+k], v1 = sh[a*28+k+1];
    acc += v0 + fi*(v1-v0);
  }
  unsigned short hb = f2bf(acc);
  float hf = __uint_as_float((unsigned)hb << 16);
  unsigned short lb = f2bf(acc - hf);
  size_t p8 = ((size_t)(y*SS + x))*8 + 5;
  hi8[p8] = hb;
  lo8[p8] = lb;
}

// ---------------- dual conv1 (7->32): implicit-GEMM MFMA on sinogram NHWC8 ----------------
__global__ __launch_bounds__(64) void dual1_mfma(
    const unsigned short* __restrict__ hi8, const unsigned short* __restrict__ lo8,  // [62][DRS][8]
    const unsigned short* __restrict__ Bimg1d,   // this layer: [3][2][2][64][8]
    const float* __restrict__ bias, const float* __restrict__ prelu,
    unsigned short* __restrict__ outHi, unsigned short* __restrict__ outLo)
{
  __shared__ unsigned int tr[64][33];
  int y  = blockIdx.y;                 // 0..59
  int lane = (int)threadIdx.x;
  int xw = blockIdx.x*64;              // 0..704
  int lm = lane & 15, lq = lane >> 4;
  f32x4 acc[4][2];
  #pragma unroll
  for (int s=0;s<4;s++){ acc[s][0] = (f32x4)0.f; acc[s][1] = (f32x4)0.f; }
  const short8* Bf = (const short8*)Bimg1d;
  #pragma unroll
  for (int g=0; g<3; g++){
    const short8* bp8 = Bf + g*256 + lane;
    short8 bh0 = bp8[0];
    short8 bl0 = bp8[64];
    short8 bh1 = bp8[128];
    short8 bl1 = bp8[192];
    int t = g*4 + lq; if (t > 8) t = 8;
    int dy = (t >= 6) ? 1 : ((t >= 3) ? 0 : -1);
    int dx = t - (dy+1)*3 - 1;
    int row = y + dy + 1;              // +1 guard-row offset
    #pragma unroll
    for (int s=0; s<4; s++){
      int px = xw + s*16 + lm + dx;
      size_t off = (size_t)(row*DRS + px)*8;
      short8 ah = *(const short8*)(hi8 + off);
      short8 al = *(const short8*)(lo8 + off);
      acc[s][0] = __builtin_amdgcn_mfma_f32_16x16x32_bf16(ah, bh0, acc[s][0], 0,0,0);
      acc[s][1] = __builtin_amdgcn_mfma_f32_16x16x32_bf16(ah, bh1, acc[s][1], 0,0,0);
      acc[s][0] = __builtin_amdgcn_mfma_f32_16x16x32_bf16(al, bh0, acc[s][0], 0,0,0);
      acc[s][1] = __builtin_amdgcn_mfma_f32_16x16x32_bf16(al, bh1, acc[s][1], 0,0,0);
      acc[s][0] = __builtin_amdgcn_mfma_f32_16x16x32_bf16(ah, bl0, acc[s][0], 0,0,0);
      acc[s][1] = __builtin_amdgcn_mfma_f32_16x16x32_bf16(ah, bl1, acc[s][1], 0,0,0);
    }
  }
  // epilogue: bias + prelu + LDS transpose -> NHWC32 hi/lo (store-masked x<=728)
  float aa = *prelu;
  #pragma unroll
  for (int s=0;s<4;s++){
    #pragma unroll
    for (int n=0;n<2;n++){
      int o = n*16 + lm;
      float bv = bias[o];
      f32x4 v = acc[s][n];
      v.x+=bv; v.y+=bv; v.z+=bv; v.w+=bv;
      v.x=(v.x>=0.f)?v.x:aa*v.x; v.y=(v.y>=0.f)?v.y:aa*v.y;
      v.z=(v.z>=0.f)?v.z:aa*v.z; v.w=(v.w>=0.f)?v.w:aa*v.w;
      #pragma unroll
      for (int r=0;r<4;r++){
        float x = v[r];
        unsigned short hb = f2bf(x);
        float hf = __uint_as_float((unsigned)hb << 16);
        unsigned short lb = f2bf(x - hf);
        tr[s*16 + lq*4 + r][o] = ((unsigned)hb << 16) | (unsigned)lb;
      }
    }
  }
  __syncthreads();
  int c8 = lane & 3;
  int pxl = lane >> 2;
  #pragma unroll
  for (int k=0;k<4;k++){
    int px = pxl + k*16;
    int x = xw + px;
    if (x > 728) continue;
    short8 vh, vl;
    #pragma unroll
    for (int j=0;j<8;j++){
      unsigned p = tr[px][c8*8 + j];
      vh[j] = (short)(p >> 16);
      vl[j] = (short)(p & 0xffffu);
    }
    size_t base = ((size_t)(y+1)*DRS + x)*32 + c8*8;
    *(short8*)(outHi + base) = vh;
    *(short8*)(outLo + base) = vl;
  }
}

// ---------------- dual conv2 (32->32): implicit-GEMM MFMA, NHWC32 bf16 hi/lo out ----------------
__global__ __launch_bounds__(64) void dual_mfma32(
    const unsigned short* __restrict__ hiB, const unsigned short* __restrict__ loB,
    const unsigned short* __restrict__ Bimg,   // this layer: [9][2][2][64][8]
    const float* __restrict__ bias, const float* __restrict__ prelu,
    unsigned short* __restrict__ outHi, unsigned short* __restrict__ outLo)
{
  __shared__ unsigned int tr[64][33];
  int y  = blockIdx.y;                               // 0..59
  int lane = (int)threadIdx.x;
  int xw = blockIdx.x*64;                            // 0..704 step 64
  int lm = lane & 15, lq = lane >> 4;
  int laneoff = lm*32 + lq*8;
  f32x4 acc[4][2];
  #pragma unroll
  for (int s=0;s<4;s++){ acc[s][0] = (f32x4)0.f; acc[s][1] = (f32x4)0.f; }
  const short8* Bf = (const short8*)Bimg;
  #pragma unroll
  for (int dy=-1; dy<=1; dy++){
    const unsigned short* rh = hiB + (size_t)(y+dy+1)*DRS*32;
    const unsigned short* rl = loB + (size_t)(y+dy+1)*DRS*32;
    #pragma unroll
    for (int dx=-1; dx<=1; dx++){
      int tap = (dy+1)*3 + (dx+1);
      const short8* bp8 = Bf + tap*256 + lane;
      short8 bh0 = bp8[0];     // n=0 hi
      short8 bl0 = bp8[64];    // n=0 lo
      short8 bh1 = bp8[128];   // n=1 hi
      short8 bl1 = bp8[192];   // n=1 lo
      int xoff = (xw + dx)*32 + laneoff;
      #pragma unroll
      for (int s=0; s<4; s++){
        short8 ah = *(const short8*)(rh + xoff + s*512);
        short8 al = *(const short8*)(rl + xoff + s*512);
        acc[s][0] = __builtin_amdgcn_mfma_f32_16x16x32_bf16(ah, bh0, acc[s][0], 0,0,0);
        acc[s][1] = __builtin_amdgcn_mfma_f32_16x16x32_bf16(ah, bh1, acc[s][1], 0,0,0);
        acc[s][0] = __builtin_amdgcn_mfma_f32_16x16x32_bf16(al, bh0, acc[s][0], 0,0,0);
        acc[s][1] = __builtin_amdgcn_mfma_f32_16x16x32_bf16(al, bh1, acc[s][1], 0,0,0);
        acc[s][0] = __builtin_amdgcn_mfma_f32_16x16x32_bf16(ah, bl0, acc[s][0], 0,0,0);
        acc[s][1] = __builtin_amdgcn_mfma_f32_16x16x32_bf16(ah, bl1, acc[s][1], 0,0,0);
      }
    }
  }
  // epilogue: bias + prelu + LDS transpose -> NHWC32 hi/lo (store-masked x<=728)
  float aa = *prelu;
  #pragma unroll
  for (int s=0;s<4;s++){
    #pragma unroll
    for (int n=0;n<2;n++){
      int o = n*16 + lm;
      float bv = bias[o];
      f32x4 v = acc[s][n];
      v.x+=bv; v.y+=bv; v.z+=bv; v.w+=bv;
      v.x=(v.x>=0.f)?v.x:aa*v.x; v.y=(v.y>=0.f)?v.y:aa*v.y;
      v.z=(v.z>=0.f)?v.z:aa*v.z; v.w=(v.w>=0.f)?v.w:aa*v.w;
      #pragma unroll
      for (int r=0;r<4;r++){
        float x = v[r];
        unsigned short hb = f2bf(x);
        float hf = __uint_as_float((unsigned)hb << 16);
        unsigned short lb = f2bf(x - hf);
        tr[s*16 + lq*4 + r][o] = ((unsigned)hb << 16) | (unsigned)lb;
      }
    }
  }
  __syncthreads();
  int c8 = lane & 3;
  int pxl = lane >> 2;
  #pragma unroll
  for (int k=0;k<4;k++){
    int px = pxl + k*16;
    int x = xw + px;
    if (x > 728) continue;
    short8 vh, vl;
    #pragma unroll
    for (int j=0;j<8;j++){
      unsigned p = tr[px][c8*8 + j];
      vh[j] = (short)(p >> 16);
      vl[j] = (short)(p & 0xffffu);
    }
    size_t base = ((size_t)(y+1)*DRS + x)*32 + c8*8;
    *(short8*)(outHi + base) = vh;
    *(short8*)(outLo + base) = vl;
  }
}

// ---------------- dual conv3 (32->5): implicit-GEMM MFMA N=16; h += ; writes s8 ch0-4 ----------------
__global__ __launch_bounds__(64) void dual3_mfma(
    const unsigned short* __restrict__ hiB, const unsigned short* __restrict__ loB,  // NHWC32 [62][DRS][32]
    const unsigned short* __restrict__ Bimg3d,   // this layer: [9][2][64][8]
    const float* __restrict__ bias,
    float* __restrict__ h,
    unsigned short* __restrict__ s8hi, unsigned short* __restrict__ s8lo)
{
  __shared__ unsigned int t8[64][6];
  int y  = blockIdx.y;                               // 0..59
  int lane = (int)threadIdx.x;
  int xw = blockIdx.x*64;                            // 0..704
  int lm = lane & 15, lq = lane >> 4;
  int laneoff = lm*32 + lq*8;
  f32x4 acc[4];
  #pragma unroll
  for (int s=0;s<4;s++) acc[s] = (f32x4)0.f;
  const short8* Bf = (const short8*)Bimg3d;
  #pragma unroll
  for (int dy=-1; dy<=1; dy++){
    const unsigned short* rh = hiB + (size_t)(y+dy+1)*DRS*32;
    const unsigned short* rl = loB + (size_t)(y+dy+1)*DRS*32;
    #pragma unroll
    for (int dx=-1; dx<=1; dx++){
      int tap = (dy+1)*3 + (dx+1);
      const short8* bp8 = Bf + tap*128 + lane;
      short8 bh = bp8[0];
      short8 bl = bp8[64];
      int xoff = (xw + dx)*32 + laneoff;
      #pragma unroll
      for (int s=0; s<4; s++){
        short8 ah = *(const short8*)(rh + xoff + s*512);
        short8 al = *(const short8*)(rl + xoff + s*512);
        acc[s] = __builtin_amdgcn_mfma_f32_16x16x32_bf16(ah, bh, acc[s], 0,0,0);
        acc[s] = __builtin_amdgcn_mfma_f32_16x16x32_bf16(al, bh, acc[s], 0,0,0);
        acc[s] = __builtin_amdgcn_mfma_f32_16x16x32_bf16(ah, bl, acc[s], 0,0,0);
      }
    }
  }
  // epilogue: h += conv3 + bias (lanes lm<5, guarded); pack updated h into LDS
  if (lm < 5){
    float bv = bias[lm];
    #pragma unroll
    for (int s=0;s<4;s++){
      int px0 = xw + s*16 + lq*4;
      float* op = h + (size_t)lm*NSIN + y*DDET + px0;
      float nv0=0.f, nv1=0.f, nv2=0.f, nv3=0.f;
      if (px0 + 3 <= 728){
        v4u old = *(const v4u*)op;
        nv0 = old.x + acc[s].x + bv;
        nv1 = old.y + acc[s].y + bv;
        nv2 = old.z + acc[s].z + bv;
        nv3 = old.w + acc[s].w + bv;
        v4u st; st.x=nv0; st.y=nv1; st.z=nv2; st.w=nv3;
        *(v4u*)op = st;
      } else {
        if (px0   <= 728){ nv0 = op[0] + acc[s].x + bv; op[0] = nv0; }
        if (px0+1 <= 728){ nv1 = op[1] + acc[s].y + bv; op[1] = nv1; }
        if (px0+2 <= 728){ nv2 = op[2] + acc[s].z + bv; op[2] = nv2; }
        if (px0+3 <= 728){ nv3 = op[3] + acc[s].w + bv; op[3] = nv3; }
      }
      float nv[4] = {nv0,nv1,nv2,nv3};
      #pragma unroll
      for (int r=0;r<4;r++){
        float x = nv[r];
        unsigned short hb = f2bf(x);
        float hf = __uint_as_float((unsigned)hb << 16);
        unsigned short lb = f2bf(x - hf);
        t8[s*16 + lq*4 + r][lm] = ((unsigned)hb << 16) | (unsigned)lb;
      }
    }
  }
  __syncthreads();
  // readout: lane = px; write NHWC8 ch0-4 (masked x<=728)
  {
    int x = xw + lane;
    if (x <= 728){
      unsigned c0 = t8[lane][0], c1 = t8[lane][1], c2 = t8[lane][2];
      unsigned c3 = t8[lane][3], c4 = t8[lane][4];
      size_t base = ((size_t)(y+1)*DRS + x)*8;
      short4v vh; vh[0]=(short)(c0>>16); vh[1]=(short)(c1>>16); vh[2]=(short)(c2>>16); vh[3]=(short)(c3>>16);
      short4v vl; vl[0]=(short)(c0&0xffffu); vl[1]=(short)(c1&0xffffu); vl[2]=(short)(c2&0xffffu); vl[3]=(short)(c3&0xffffu);
      *(short4v*)(s8hi + base) = vh;
      *(short4v*)(s8lo + base) = vl;
      s8hi[base+4] = (unsigned short)(c4>>16);
      s8lo[base+4] = (unsigned short)(c4&0xffffu);
    }
  }
}

// ---------------- primal conv1 (6->32): implicit-GEMM MFMA on NHWC8 input ----------------
__global__ __launch_bounds__(256) void prim1_mfma(
    const unsigned short* __restrict__ hi8, const unsigned short* __restrict__ lo8,  // [512][512][8]
    const unsigned short* __restrict__ Bimg1,   // this layer: [3][2][2][64][8]
    const float* __restrict__ bias, const float* __restrict__ prelu,
    unsigned short* __restrict__ outHi, unsigned short* __restrict__ outLo)
{
  __shared__ unsigned int tr[4][64][33];
  int b = blockIdx.x;                 // 0..1023
  int by = b >> 1, half = b & 1;
  int y = ((by & 7) << 6) | (by >> 3);   // XCD row swizzle
  int wv = (int)threadIdx.x >> 6;
  int lane = (int)threadIdx.x & 63;
  int xw = half*256 + wv*64;
  int lm = lane & 15, lq = lane >> 4;
  f32x4 acc[4][2];
  #pragma unroll
  for (int s=0;s<4;s++){ acc[s][0] = (f32x4)0.f; acc[s][1] = (f32x4)0.f; }
  bool fast = (y>0) && (y<511) && (xw!=0) && (xw!=448);
  const short8* Bf = (const short8*)Bimg1;
  #pragma unroll
  for (int g=0; g<3; g++){
    const short8* bp8 = Bf + g*256 + lane;
    short8 bh0 = bp8[0];
    short8 bl0 = bp8[64];
    short8 bh1 = bp8[128];
    short8 bl1 = bp8[192];
    int t = g*4 + lq; if (t > 8) t = 8;
    int dy = (t >= 6) ? 1 : ((t >= 3) ? 0 : -1);
    int dx = t - (dy+1)*3 - 1;
    int row = y + dy;
    #pragma unroll
    for (int s=0; s<4; s++){
      short8 ah, al;
      int px = xw + s*16 + lm + dx;
      if (fast){
        size_t off = ((size_t)row*SS + px)*8;
        ah = *(const short8*)(hi8 + off);
        al = *(const short8*)(lo8 + off);
      } else {
        bool ok = ((unsigned)row < 512u) && ((unsigned)px < 512u);
        size_t off = ok ? ((size_t)row*SS + px)*8 : 0;
        ah = ok ? *(const short8*)(hi8 + off) : (short8)0;
        al = ok ? *(const short8*)(lo8 + off) : (short8)0;
      }
      acc[s][0] = __builtin_amdgcn_mfma_f32_16x16x32_bf16(ah, bh0, acc[s][0], 0,0,0);
      acc[s][1] = __builtin_amdgcn_mfma_f32_16x16x32_bf16(ah, bh1, acc[s][1], 0,0,0);
      acc[s][0] = __builtin_amdgcn_mfma_f32_16x16x32_bf16(al, bh0, acc[s][0], 0,0,0);
      acc[s][1] = __builtin_amdgcn_mfma_f32_16x16x32_bf16(al, bh1, acc[s][1], 0,0,0);
      acc[s][0] = __builtin_amdgcn_mfma_f32_16x16x32_bf16(ah, bl0, acc[s][0], 0,0,0);
      acc[s][1] = __builtin_amdgcn_mfma_f32_16x16x32_bf16(ah, bl1, acc[s][1], 0,0,0);
    }
  }
  // epilogue: bias + prelu + pack hi/lo into LDS [px][ch], NHWC32 stores
  float aa = *prelu;
  #pragma unroll
  for (int s=0;s<4;s++){
    #pragma unroll
    for (int n=0;n<2;n++){
      int o = n*16 + lm;
      float bv = bias[o];
      f32x4 v = acc[s][n];
      v.x+=bv; v.y+=bv; v.z+=bv; v.w+=bv;
      v.x=(v.x>=0.f)?v.x:aa*v.x; v.y=(v.y>=0.f)?v.y:aa*v.y;
      v.z=(v.z>=0.f)?v.z:aa*v.z; v.w=(v.w>=0.f)?v.w:aa*v.w;
      #pragma unroll
      for (int r=0;r<4;r++){
        float x = v[r];
        unsigned short hb = f2bf(x);
        float hf = __uint_as_float((unsigned)hb << 16);
        unsigned short lb = f2bf(x - hf);
        tr[wv][s*16 + lq*4 + r][o] = ((unsigned)hb << 16) | (unsigned)lb;
      }
    }
  }
  __syncthreads();
  int c8 = lane & 3;
  int pxl = lane >> 2;
  #pragma unroll
  for (int k=0;k<4;k++){
    int px = pxl + k*16;
    short8 vh, vl;
    #pragma unroll
    for (int j=0;j<8;j++){
      unsigned p = tr[wv][px][c8*8 + j];
      vh[j] = (short)(p >> 16);
      vl[j] = (short)(p & 0xffffu);
    }
    size_t base = ((size_t)(y*SS + xw + px))*32 + c8*8;
    *(short8*)(outHi + base) = vh;
    *(short8*)(outLo + base) = vl;
  }
}

// ---------------- primal conv2 (32->32): implicit-GEMM MFMA bf16 hi/lo ----------------
__global__ __launch_bounds__(256) void conv_mfma32(
    const unsigned short* __restrict__ hiB, const unsigned short* __restrict__ loB,
    const unsigned short* __restrict__ Bimg,   // this layer: [9][2][2][64][8]
    const float* __restrict__ bias, const float* __restrict__ prelu,
    unsigned short* __restrict__ outHi, unsigned short* __restrict__ outLo)
{
  __shared__ unsigned int tr[4][64][33];
  int b = blockIdx.x;                 // 0..1023
  int by = b >> 1, half = b & 1;
  int y = ((by & 7) << 6) | (by >> 3);   // XCD row swizzle
  int wv = (int)threadIdx.x >> 6;
  int lane = (int)threadIdx.x & 63;
  int xw = half*256 + wv*64;
  int lm = lane & 15, lq = lane >> 4;
  int laneoff = lm*32 + lq*8;
  f32x4 acc[4][2];
  #pragma unroll
  for (int s=0;s<4;s++){ acc[s][0] = (f32x4)0.f; acc[s][1] = (f32x4)0.f; }
  bool fastx = (xw != 0) && (xw != 448);
  const short8* Bf = (const short8*)Bimg;
  #pragma unroll
  for (int dy=-1; dy<=1; dy++){
    int yy = y + dy;
    if ((unsigned)yy >= 512u) continue;
    const unsigned short* rh = hiB + (size_t)yy*512*32;
    const unsigned short* rl = loB + (size_t)yy*512*32;
    #pragma unroll
    for (int dx=-1; dx<=1; dx++){
      int tap = (dy+1)*3 + (dx+1);
      const short8* bp8 = Bf + tap*256 + lane;
      short8 bh0 = bp8[0];     // n=0 hi
      short8 bl0 = bp8[64];    // n=0 lo
      short8 bh1 = bp8[128];   // n=1 hi
      short8 bl1 = bp8[192];   // n=1 lo
      int xoff = (xw + dx)*32 + laneoff;
      #pragma unroll
      for (int s=0; s<4; s++){
        short8 ah, al;
        const unsigned short* ph = rh + xoff + s*512;
        const unsigned short* pl = rl + xoff + s*512;
        if (fastx){
          ah = *(const short8*)ph;
          al = *(const short8*)pl;
        } else {
          int x = xw + s*16 + lm + dx;
          bool ok = ((unsigned)x < 512u);
          ah = ok ? *(const short8*)ph : (short8)0;
          al = ok ? *(const short8*)pl : (short8)0;
        }
        acc[s][0] = __builtin_amdgcn_mfma_f32_16x16x32_bf16(ah, bh0, acc[s][0], 0,0,0);
        acc[s][1] = __builtin_amdgcn_mfma_f32_16x16x32_bf16(ah, bh1, acc[s][1], 0,0,0);
        acc[s][0] = __builtin_amdgcn_mfma_f32_16x16x32_bf16(al, bh0, acc[s][0], 0,0,0);
        acc[s][1] = __builtin_amdgcn_mfma_f32_16x16x32_bf16(al, bh1, acc[s][1], 0,0,0);
        acc[s][0] = __builtin_amdgcn_mfma_f32_16x16x32_bf16(ah, bl0, acc[s][0], 0,0,0);
        acc[s][1] = __builtin_amdgcn_mfma_f32_16x16x32_bf16(ah, bl1, acc[s][1], 0,0,0);
      }
    }
  }
  // epilogue: bias + prelu + pack hi/lo into LDS [px][ch]
  float aa = *prelu;
  #pragma unroll
  for (int s=0;s<4;s++){
    #pragma unroll
    for (int n=0;n<2;n++){
      int o = n*16 + lm;
      float bv = bias[o];
      f32x4 v = acc[s][n];
      v.x+=bv; v.y+=bv; v.z+=bv; v.w+=bv;
      v.x=(v.x>=0.f)?v.x:aa*v.x; v.y=(v.y>=0.f)?v.y:aa*v.y;
      v.z=(v.z>=0.f)?v.z:aa*v.z; v.w=(v.w>=0.f)?v.w:aa*v.w;
      #pragma unroll
      for (int r=0;r<4;r++){
        float x = v[r];
        unsigned short hb = f2bf(x);
        float hf = __uint_as_float((unsigned)hb << 16);
        unsigned short lb = f2bf(x - hf);
        tr[wv][s*16 + lq*4 + r][o] = ((unsigned)hb << 16) | (unsigned)lb;
      }
    }
  }
  __syncthreads();
  // read channel-contiguous, split, coalesced NHWC stores
  int c8 = lane & 3;             // 8-channel chunk
  int pxl = lane >> 2;           // 0..15
  #pragma unroll
  for (int k=0;k<4;k++){
    int px = pxl + k*16;
    short8 vh, vl;
    #pragma unroll
    for (int j=0;j<8;j++){
      unsigned p = tr[wv][px][c8*8 + j];
      vh[j] = (short)(p >> 16);
      vl[j] = (short)(p & 0xffffu);
    }
    size_t base = ((size_t)(y*SS + xw + px))*32 + c8*8;
    *(short8*)(outHi + base) = vh;
    *(short8*)(outLo + base) = vl;
  }
}

// ---------------- primal conv3 (32->5): implicit-GEMM MFMA, N=16 (5 real) ----------------
__global__ __launch_bounds__(256) void duo_mfma(
    const unsigned short* __restrict__ hiB, const unsigned short* __restrict__ loB,
    const unsigned short* __restrict__ Bimg3,   // this layer: [9][2][64][8]
    const float* __restrict__ bias,
    float* __restrict__ f,
    float* __restrict__ fout, float* __restrict__ tout,
    unsigned short* __restrict__ hi8, unsigned short* __restrict__ lo8)
{
  __shared__ unsigned int t8[4][64][6];
  int b = blockIdx.x;                 // 0..1023
  int by = b >> 1, half = b & 1;
  int y = ((by & 7) << 6) | (by >> 3);   // XCD row swizzle
  int wv = (int)threadIdx.x >> 6;
  int lane = (int)threadIdx.x & 63;
  int xw = half*256 + wv*64;
  int lm = lane & 15, lq = lane >> 4;
  int laneoff = lm*32 + lq*8;
  f32x4 acc[4];
  #pragma unroll
  for (int s=0;s<4;s++) acc[s] = (f32x4)0.f;
  bool fastx = (xw != 0) && (xw != 448);
  const short8* Bf = (const short8*)Bimg3;
  #pragma unroll
  for (int dy=-1; dy<=1; dy++){
    int yy = y + dy;
    if ((unsigned)yy >= 512u) continue;
    const unsigned short* rh = hiB + (size_t)yy*512*32;
    const unsigned short* rl = loB + (size_t)yy*512*32;
    #pragma unroll
    for (int dx=-1; dx<=1; dx++){
      int tap = (dy+1)*3 + (dx+1);
      const short8* bp8 = Bf + tap*128 + lane;
      short8 bh = bp8[0];
      short8 bl = bp8[64];
      int xoff = (xw + dx)*32 + laneoff;
      #pragma unroll
      for (int s=0; s<4; s++){
        short8 ah, al;
        const unsigned short* ph = rh + xoff + s*512;
        const unsigned short* pl = rl + xoff + s*512;
        if (fastx){
          ah = *(const short8*)ph;
          al = *(const short8*)pl;
        } else {
          int x = xw + s*16 + lm + dx;
          bool ok = ((unsigned)x < 512u);
          ah = ok ? *(const short8*)ph : (short8)0;
          al = ok ? *(const short8*)pl : (short8)0;
        }
        acc[s] = __builtin_amdgcn_mfma_f32_16x16x32_bf16(ah, bh, acc[s], 0,0,0);
        acc[s] = __builtin_amdgcn_mfma_f32_16x16x32_bf16(al, bh, acc[s], 0,0,0);
        acc[s] = __builtin_amdgcn_mfma_f32_16x16x32_bf16(ah, bl, acc[s], 0,0,0);
      }
    }
  }
  // epilogue: f += conv3 + bias on lanes lm<5; imgT transpose (lm==1); output rep (lm==0)
  if (lm < 5){
    float bv = bias[lm];
    #pragma unroll
    for (int s=0;s<4;s++){
      int px0 = xw + s*16 + lq*4;
      float* op = f + (size_t)lm*NPIX + y*SS + px0;
      f32x4 old = *(const f32x4*)op;
      f32x4 v = acc[s];
      v.x += old.x + bv; v.y += old.y + bv;
      v.z += old.z + bv; v.w += old.w + bv;
      *(f32x4*)op = v;
      #pragma unroll
      for (int r=0;r<4;r++){
        float x = v[r];
        unsigned short hb = f2bf(x);
        float hf = __uint_as_float((unsigned)hb << 16);
        unsigned short lb = f2bf(x - hf);
        t8[wv][s*16 + lq*4 + r][lm] = ((unsigned)hb << 16) | (unsigned)lb;
      }
      if (lm == 1){
        tout[(px0  )*SS + y] = v.x;
        tout[(px0+1)*SS + y] = v.y;
        tout[(px0+2)*SS + y] = v.z;
        tout[(px0+3)*SS + y] = v.w;
      }
      if (lm == 0 && fout){
        float* q = fout + y*SS + px0;
        *(f32x4*)q = v;
        *(f32x4*)(q + NPIX) = v;
        *(f32x4*)(q + 2*NPIX) = v;
      }
    }
  }
  __syncthreads();
  // readout: lane = px; write NHWC8 ch0-4 (8B + 2B stores, hi and lo)
  {
    unsigned c0 = t8[wv][lane][0], c1 = t8[wv][lane][1], c2 = t8[wv][lane][2];
    unsigned c3 = t8[wv][lane][3], c4 = t8[wv][lane][4];
    size_t base = ((size_t)(y*SS + xw + lane))*8;
    short4v vh; vh[0]=(short)(c0>>16); vh[1]=(short)(c1>>16); vh[2]=(short)(c2>>16); vh[3]=(short)(c3>>16);
    short4v vl; vl[0]=(short)(c0&0xffffu); vl[1]=(short)(c1&0xffffu); vl[2]=(short)(c2&0xffffu); vl[3]=(short)(c3&0xffffu);
    *(short4v*)(hi8 + base) = vh;
    *(short4v*)(lo8 + base) = vl;
    hi8[base+4] = (unsigned short)(c4>>16);
    lo8[base+4] = (unsigned short)(c4&0xffffu);
  }
}

extern "C" void kernel_launch(void* const* d_in, const int* in_sizes, int n_in,
                              void* d_out, int out_size, void* d_ws, size_t ws_size,
                              hipStream_t stream){
  const float* g     = (const float*)d_in[2];
  const float* theta = (const float*)d_in[3];
  const float* dw1 = (const float*)d_in[5];
  const float* db1 = (const float*)d_in[6];
  const float* da1 = (const float*)d_in[7];
  const float* dw2 = (const float*)d_in[8];
  const float* db2 = (const float*)d_in[9];
  const float* da2 = (const float*)d_in[10];
  const float* dw3 = (const float*)d_in[11];
  const float* db3 = (const float*)d_in[12];
  const float* pw1 = (const float*)d_in[13];
  const float* pb1 = (const float*)d_in[14];
  const float* pa1 = (const float*)d_in[15];
  const float* pw2 = (const float*)d_in[16];
  const float* pb2 = (const float*)d_in[17];
  const float* pa2 = (const float*)d_in[18];
  const float* pw3 = (const float*)d_in[19];
  const float* pb3 = (const float*)d_in[20];

  float* ws     = (float*)d_ws;
  float* trig   = ws;                    // 128
  float* taps   = ws + 128;              // -> 2048
  float* h      = ws + 2048;             // 5*NSIN
  float* opf    = h + 5*NSIN;            // NSIN (unused, keeps layout)
  float* gcopy  = opf + NSIN;            // NSIN (unused, keeps layout)
  float* h1     = gcopy + NSIN;          // NSIN
  float* f      = h1 + NSIN;             // 5*NPIX
  float* bp     = f + 5*NPIX;            // NPIX (unused, keeps layout)
  float* imgT   = bp + NPIX;             // NPIX
  float* dualT1 = imgT + NPIX;           // 32*NSIN slot -> dual2Hi
  float* dualT2 = dualT1 + 32*NSIN;      // 32*NSIN slot -> dual2Lo
  float* primT2slot = dualT2 + 32*NSIN;  // 32*NPIX floats of space
  unsigned short* primHi = (unsigned short*)primT2slot;          // 32*NPIX ushorts
  unsigned short* primLo = primHi + (size_t)32*NPIX;             // 32*NPIX ushorts
  unsigned short* nhwcHi = (unsigned short*)(primT2slot + 32*NPIX);  // 32*NPIX ushorts
  unsigned short* nhwcLo = nhwcHi + (size_t)32*NPIX;             // 32*NPIX ushorts
  float* wsp   = (float*)(nhwcLo + (size_t)32*NPIX);
  unsigned short* Bimg  = (unsigned short*)(wsp + 158400);       // 184320 ushorts
  unsigned short* Bimg2 = Bimg + 184320;                         // 184320 ushorts
  unsigned short* Bimg3 = Bimg2 + 184320;                        // 92160 ushorts
  unsigned short* Bimg1 = Bimg3 + 92160;                         // 61440 ushorts
  unsigned short* Bimg1d = Bimg1 + 61440;                        // 61440 ushorts
  unsigned short* Bimg3d = Bimg1d + 61440;                       // 92160 ushorts
  // dual NHWC32 hi/lo: 62 rows x DRS x 32ch + 64-ushort zero prefix/suffix
  const size_t DUALSZ = (size_t)64 + (size_t)62*DRS*32 + 64;
  unsigned short* dualHiRaw = Bimg3d + 92160;
  unsigned short* dualLoRaw = dualHiRaw + DUALSZ;
  unsigned short* dualHi = dualHiRaw + 64;
  unsigned short* dualLo = dualLoRaw + 64;
  // dual conv2 NHWC32 output in recycled dualT1/dualT2 slots
  unsigned short* dual2HiRaw = (unsigned short*)dualT1;
  unsigned short* dual2LoRaw = (unsigned short*)dualT2;
  unsigned short* dual2Hi = dual2HiRaw + 64;
  unsigned short* dual2Lo = dual2LoRaw + 64;
  // primal NHWC8 input image [512][512][8] bf16 hi/lo
  unsigned short* nh8Hi = dualLoRaw + DUALSZ;
  unsigned short* nh8Lo = nh8Hi + (size_t)NPIX*8;
  // sinogram NHWC8 input image [62][DRS][8] bf16 hi/lo + 64-ushort prefix/suffix
  const size_t S8SZ = (size_t)64 + (size_t)62*DRS*8 + 64;
  unsigned short* s8HiRaw = nh8Lo + (size_t)NPIX*8;
  unsigned short* s8LoRaw = s8HiRaw + S8SZ;
  unsigned short* s8Hi = s8HiRaw + 64;
  unsigned short* s8Lo = s8LoRaw + 64;

  hipMemsetAsync(h, 0, (size_t)(5*NSIN)*sizeof(float), stream);
  hipMemsetAsync(f, 0, (size_t)(7*NPIX)*sizeof(float), stream);   // f, bp, imgT
  hipMemsetAsync(dualHiRaw, 0, 2*DUALSZ*sizeof(unsigned short), stream);  // zero pads once
  hipMemsetAsync(dual2HiRaw, 0, DUALSZ*sizeof(unsigned short), stream);   // zero pads once
  hipMemsetAsync(dual2LoRaw, 0, DUALSZ*sizeof(unsigned short), stream);   // zero pads once
  hipMemsetAsync(nh8Hi, 0, (size_t)2*NPIX*8*sizeof(unsigned short), stream); // zero once
  hipMemsetAsync(s8HiRaw, 0, 2*S8SZ*sizeof(unsigned short), stream); // zero once
  trig_kernel<<<1,64,0,stream>>>(theta, trig);
  taps_kernel<<<NTAPS,256,0,stream>>>(taps);
  prep_bimg<<<(92160+255)/256,256,0,stream>>>(pw2, Bimg);
  prep_bimg<<<(92160+255)/256,256,0,stream>>>(dw2, Bimg2);
  prep_bimg3<<<(46080+255)/256,256,0,stream>>>(pw3, Bimg3);
  prep_bimg3<<<(46080+255)/256,256,0,stream>>>(dw3, Bimg3d);
  prep_bimg1c<<<(30720+255)/256,256,0,stream>>>(pw1, Bimg1, 6);
  prep_bimg1c<<<(30720+255)/256,256,0,stream>>>(dw1, Bimg1d, 7);
  g_to_nhwc8<<<(NSIN+255)/256,256,0,stream>>>(g, s8Hi, s8Lo);

  for (int i=0;i<10;i++){
    radon_fwd_kernel<<<(NSIN+3)/4,256,0,stream>>>(f + NPIX, imgT, trig, s8Hi, s8Lo);
    // dual block: NHWC8 [h(5)|opf|g|0] -> conv1 -> conv2 -> conv3 (all MFMA)
    dual1_mfma<<<dim3(12,AANG),64,0,stream>>>(s8Hi, s8Lo, Bimg1d+(size_t)i*6144,
                                              db1+(size_t)i*32, da1+i, dualHi, dualLo);
    dual_mfma32<<<dim3(12,AANG),64,0,stream>>>(dualHi, dualLo, Bimg2+(size_t)i*18432,
                                               db2+(size_t)i*32, da2+i, dual2Hi, dual2Lo);
    dual3_mfma<<<dim3(12,AANG),64,0,stream>>>(dual2Hi, dual2Lo, Bimg3d+(size_t)i*9216,
                                              db3+(size_t)i*5, h, s8Hi, s8Lo);
    filter_kernel2<<<AANG*12,256,0,stream>>>(h, taps, h1);
    backproj_kernel<<<NPIX/256,256,0,stream>>>(h1, trig, nh8Hi, nh8Lo);
    // primal block: NHWC8 [f(5)|bp|0|0] -> conv1 -> conv2 -> conv3
    prim1_mfma<<<1024,256,0,stream>>>(nh8Hi, nh8Lo, Bimg1+(size_t)i*6144,
                                      pb1+(size_t)i*32, pa1+i, nhwcHi, nhwcLo);
    conv_mfma32<<<1024,256,0,stream>>>(nhwcHi, nhwcLo, Bimg+(size_t)i*18432, pb2+(size_t)i*32, pa2+i, primHi, primLo);
    duo_mfma<<<1024,256,0,stream>>>(primHi, primLo, Bimg3+(size_t)i*9216, pb3+(size_t)i*5, f,
                                    (i==9) ? (float*)d_out : nullptr, imgT, nh8Hi, nh8Lo);
  }
}

// Round 10
// 1728.536 us; speedup vs baseline: 3.8485x; 1.0375x over previous
//
#include <hip/hip_runtime.h>
#include <math.h>

#define SS 512
#define AANG 60
#define DDET 729
#define NPIX (SS*SS)        // 262144
#define NSIN (AANG*DDET)    // 43740
#define NTAPS 1457
#define DRS 768             // dual NHWC padded row stride

typedef float v4u __attribute__((ext_vector_type(4), aligned(4)));
typedef float v2u __attribute__((ext_vector_type(2), aligned(8)));
typedef short short8 __attribute__((ext_vector_type(8)));
typedef short short4v __attribute__((ext_vector_type(4)));
typedef float f32x4 __attribute__((ext_vector_type(4)));

// round-to-nearest-even fp32 -> bf16 bits
__device__ inline unsigned short f2bf(float x){
  unsigned u = __float_as_uint(x);
  return (unsigned short)((u + 0x7fffu + ((u >> 16) & 1u)) >> 16);
}

__device__ inline unsigned pack_hilo(float x){
  unsigned short hb = f2bf(x);
  float hf = __uint_as_float((unsigned)hb << 16);
  unsigned short lb = f2bf(x - hf);
  return ((unsigned)hb << 16) | (unsigned)lb;
}

// ---------------- trig table ----------------
__global__ void trig_kernel(const float* __restrict__ theta, float* __restrict__ trig){
  int a = threadIdx.x;
  if (a < AANG){ trig[a] = cosf(theta[a]); trig[AANG+a] = sinf(theta[a]); }
}

// ---------------- ramp-filter taps ----------------
__global__ void taps_kernel(float* __restrict__ taps){
  __shared__ double red[256];
  int m  = blockIdx.x;
  int mm = m - 728;
  double s = 0.0;
  for (int k = 1 + (int)threadIdx.x; k <= 1023; k += 256){
    int phase = (k*mm) & 2047;
    s += (double)k * cos((double)phase * (M_PI/1024.0));
  }
  red[threadIdx.x] = s;
  __syncthreads();
  for (int off=128; off; off>>=1){
    if ((int)threadIdx.x < off) red[threadIdx.x] += red[threadIdx.x+off];
    __syncthreads();
  }
  if (threadIdx.x==0){
    double x = (red[0]*(1.0/512.0) + ((mm & 1) ? -1.0 : 1.0)) / 2048.0;
    taps[m] = (float)(x * (M_PI/120.0));
  }
}

// -------- MFMA B-fragment image: [L][tap=9][n=2][prod=2][lane=64][8] bf16 --------
// works for any [L][32][32][3][3] weight tensor (pw2 and dw2)
__global__ void prep_bimg(const float* __restrict__ w, unsigned short* __restrict__ B){
  int idx = blockIdx.x*256 + (int)threadIdx.x;
  if (idx >= 10*9*2*64*8) return;
  int j    =  idx        & 7;
  int lane = (idx >> 3)  & 63;
  int n    = (idx >> 9)  & 1;
  int r    =  idx >> 10;          // l*9 + tap
  int tap = r % 9, l = r / 9;
  int c = (lane >> 4)*8 + j;      // k = channel
  int o = n*16 + (lane & 15);     // output channel
  float x = w[(((size_t)(l*32+o)*32 + c)*9) + tap];
  unsigned short hb = f2bf(x);
  float hf = __uint_as_float((unsigned)hb << 16);
  unsigned short lb = f2bf(x - hf);
  size_t d = (size_t)l*18432 + (size_t)tap*2048 + n*1024 + lane*8 + j;
  B[d]       = hb;
  B[d + 512] = lb;
}

// -------- MFMA B-fragment image for [L][5][32][3][3]: [L][tap=9][prod=2][lane=64][8] --------
__global__ void prep_bimg3(const float* __restrict__ w, unsigned short* __restrict__ B){
  int idx = blockIdx.x*256 + (int)threadIdx.x;
  if (idx >= 10*9*64*8) return;
  int j    =  idx       & 7;
  int lane = (idx >> 3) & 63;
  int r    =  idx >> 9;           // l*9 + tap
  int tap = r % 9, l = r / 9;
  int c = (lane >> 4)*8 + j;      // k = channel
  int o = lane & 15;              // output channel (5 real)
  float x = (o < 5) ? w[(((size_t)(l*5+o)*32 + c)*9) + tap] : 0.f;
  unsigned short hb = f2bf(x);
  float hf = __uint_as_float((unsigned)hb << 16);
  unsigned short lb = f2bf(x - hf);
  size_t d = (size_t)l*9216 + (size_t)tap*1024 + lane*8 + j;
  B[d]       = hb;
  B[d + 512] = lb;
}

// -------- MFMA B-fragment image for NHWC8 conv1 weights [L][32][Cin][3][3] --------
// layout [L][g=3][n=2][prod=2][64][8]; k = tap_local*8 + ch; t = g*4+tap_local
__global__ void prep_bimg1c(const float* __restrict__ w, unsigned short* __restrict__ B, int Cin){
  int idx = blockIdx.x*256 + (int)threadIdx.x;
  if (idx >= 10*3*2*64*8) return;
  int j    =  idx       & 7;
  int lane = (idx >> 3) & 63;
  int n    = (idx >> 9) & 1;
  int r    =  idx >> 10;          // l*3 + g
  int g = r % 3, l = r / 3;
  int t = g*4 + (lane >> 4);
  int o = n*16 + (lane & 15);
  float x = (t < 9 && j < Cin) ? w[(((size_t)(l*32+o)*Cin + j)*9) + t] : 0.f;
  unsigned short hb = f2bf(x);
  float hf = __uint_as_float((unsigned)hb << 16);
  unsigned short lb = f2bf(x - hf);
  size_t d = (size_t)l*6144 + (size_t)g*2048 + n*1024 + lane*8 + j;
  B[d]       = hb;
  B[d + 512] = lb;
}

// ---------------- g -> sinogram NHWC8 ch6 (once) ----------------
__global__ void g_to_nhwc8(const float* __restrict__ g,
                           unsigned short* __restrict__ s8hi, unsigned short* __restrict__ s8lo){
  int idx = blockIdx.x*256 + (int)threadIdx.x;
  if (idx >= NSIN) return;
  int a = idx / DDET, d = idx - a*DDET;
  unsigned p = pack_hilo(g[idx]);
  size_t p8 = ((size_t)(a+1)*DRS + d)*8 + 6;
  s8hi[p8] = (unsigned short)(p >> 16);
  s8lo[p8] = (unsigned short)(p & 0xffffu);
}

// ---------------- radon forward: rcp-hoisted clip; writes NHWC8sin ch5 ----------------
__device__ inline void clipr(float al, float ial, float be, float lo, float hi,
                             float& A, float& B, bool& empty){
  if (fabsf(al) < 1e-7f){ if (be < lo || be > hi) empty = true; return; }
  float t0 = (lo - be)*ial, t1 = (hi - be)*ial;
  float mn = fminf(t0,t1), mx = fmaxf(t0,t1);
  A = fmaxf(A, mn); B = fminf(B, mx);
}

__device__ inline float samp_guard(const float* __restrict__ base, float aR, float bR,
                                   float aC, float bC, int t){
  float tp = (float)t - 255.5f;
  float R = fmaf(aR, tp, bR);
  float C = fmaf(aC, tp, bC);
  float rf = floorf(R), cf = floorf(C);
  int r0 = (int)rf, c0 = (int)cf;
  int r1 = r0+1,    c1 = c0+1;
  float fr = R - rf, fc = C - cf;
  bool r0ok = (r0>=0 && r0<SS), r1ok = (r1>=0 && r1<SS);
  bool c0ok = (c0>=0 && c0<SS), c1ok = (c1>=0 && c1<SS);
  float v00 = (r0ok && c0ok) ? base[r0*SS+c0] : 0.f;
  float v01 = (r0ok && c1ok) ? base[r0*SS+c1] : 0.f;
  float v10 = (r1ok && c0ok) ? base[r1*SS+c0] : 0.f;
  float v11 = (r1ok && c1ok) ? base[r1*SS+c1] : 0.f;
  return (1.f-fr)*((1.f-fc)*v00 + fc*v01) + fr*((1.f-fc)*v10 + fc*v11);
}

__global__ __launch_bounds__(256) void radon_fwd_kernel(
    const float* __restrict__ img, const float* __restrict__ imgT,
    const float* __restrict__ trig,
    unsigned short* __restrict__ s8hi, unsigned short* __restrict__ s8lo){
  int gid  = blockIdx.x*4 + ((int)threadIdx.x >> 6);
  int lane = (int)threadIdx.x & 63;
  if (gid >= NSIN) return;
  int a = gid / DDET;
  int d = gid - a*DDET;
  float ca = trig[a], sa = trig[AANG+a];
  float sd = (float)d - 364.0f;
  float Rc = fmaf(sd, sa, 255.5f);
  float Cc = fmaf(sd, ca, 255.5f);
  float aR = ca, bR = Rc, aC = -sa, bC = Cc;
  const float* base = img;
  if (fabsf(ca) > fabsf(sa)){
    base = imgT;
    float tmp;
    tmp=aR; aR=aC; aC=tmp;
    tmp=bR; bR=bC; bC=tmp;
  }
  float iaR = __builtin_amdgcn_rcpf(aR);
  float iaC = __builtin_amdgcn_rcpf(aC);
  float tiA = -255.5f, tiB = 255.5f;  bool iE=false;
  float teA = -255.5f, teB = 255.5f;  bool eE=false;
  clipr(aR,iaR,bR, 0.001f, 510.999f, tiA,tiB,iE);
  clipr(aC,iaC,bC, 0.001f, 510.999f, tiA,tiB,iE);
  clipr(aR,iaR,bR, -0.999f, 511.999f, teA,teB,eE);
  clipr(aC,iaC,bC, -0.999f, 511.999f, teA,teB,eE);
  float acc = 0.f;
  if (!eE && teA <= teB){
    int eA = max(0,   (int)floorf(teA+255.5f) - 1);
    int eB = min(511, (int)ceilf (teB+255.5f) + 1);
    int iA = (int)ceilf (tiA+255.5f) + 1;
    int iB = (int)floorf(tiB+255.5f) - 1;
    iA = max(iA, eA); iB = min(iB, eB);
    if (iE || iA > iB){
      for (int t = eA+lane; t <= eB; t += 64) acc += samp_guard(base,aR,bR,aC,bC,t);
    } else {
      for (int t = eA+lane;   t <  iA; t += 64) acc += samp_guard(base,aR,bR,aC,bC,t);
      for (int t = iB+1+lane; t <= eB; t += 64) acc += samp_guard(base,aR,bR,aC,bC,t);
      for (int t = iA+lane;   t <= iB; t += 64){
        float tp = (float)t - 255.5f;
        float R = fmaf(aR, tp, bR);
        float C = fmaf(aC, tp, bC);
        int r0 = (int)R, c0 = (int)C;
        float fr = R - (float)r0, fc = C - (float)c0;
        const float* p = base + r0*SS + c0;
        float v00 = p[0], v01 = p[1], v10 = p[SS], v11 = p[SS+1];
        float top = v00 + fc*(v01-v00);
        float bot = v10 + fc*(v11-v10);
        acc += top + fr*(bot-top);
      }
    }
  }
  for (int off=32; off; off>>=1) acc += __shfl_down(acc, off);
  if (lane==0){
    unsigned p = pack_hilo(acc);
    size_t p8 = ((size_t)(a+1)*DRS + d)*8 + 5;
    s8hi[p8] = (unsigned short)(p >> 16);
    s8lo[p8] = (unsigned short)(p & 0xffffu);
  }
}

// ---------------- ramp filter: 4-way k-split, 64 outputs/block ----------------
__global__ __launch_bounds__(256) void filter_kernel2(
    const float* __restrict__ h0, const float* __restrict__ taps,
    float* __restrict__ h1){
  __shared__ float red[256];
  int a  = blockIdx.x / 12;
  int jb = blockIdx.x - a*12;
  int jl = (int)threadIdx.x & 63;
  int kq = (int)threadIdx.x >> 6;
  int j  = jb*64 + jl;
  float acc = 0.f;
  if (j < DDET){
    const float* row = h0 + a*DDET;
    const float* tp  = taps + 728 + j;
    int k0 = kq*183;
    int k1 = min(k0+183, DDET);
    for (int k=k0;k<k1;k++) acc = fmaf(row[k], tp[-k], acc);
  }
  red[threadIdx.x] = acc;
  __syncthreads();
  if ((int)threadIdx.x < 64 && j < DDET){
    float s = red[jl] + red[64+jl] + red[128+jl] + red[192+jl];
    h1[a*DDET + j] = s;
  }
}

// ---------------- backprojection: writes NHWC8 ch5 bf16 hi/lo ----------------
__global__ __launch_bounds__(256) void backproj_kernel(
    const float* __restrict__ h1, const float* __restrict__ trig,
    unsigned short* __restrict__ hi8, unsigned short* __restrict__ lo8){
  __shared__ float sh[AANG*28];
  __shared__ int   sbase[AANG];
  __shared__ float strig[2*AANG];
  int tid = threadIdx.x;
  int x0 = (blockIdx.x & 31) * 16, y0 = (blockIdx.x >> 5) * 16;
  if (tid < 2*AANG) strig[tid] = trig[tid];
  __syncthreads();
  if (tid < AANG){
    float ca = strig[tid], sa = strig[AANG+tid];
    float Xa = (float)x0 - 255.5f, Xb = Xa + 15.f;
    float Ya = (float)y0 - 255.5f, Yb = Ya + 15.f;
    float s00 = Xa*ca + Ya*sa, s01 = Xb*ca + Ya*sa;
    float s10 = Xa*ca + Yb*sa, s11 = Xb*ca + Yb*sa;
    float mn = fminf(fminf(s00,s01), fminf(s10,s11)) + 364.0f;
    sbase[tid] = (int)floorf(mn) - 2;
  }
  __syncthreads();
  for (int s = tid; s < AANG*28; s += 256){
    int a = s / 28, j = s - a*28;
    int idx = sbase[a] + j;
    sh[s] = (idx >= 0 && idx < DDET) ? h1[a*DDET + idx] : 0.f;
  }
  __syncthreads();
  int x = x0 + (tid & 15), y = y0 + (tid >> 4);
  float X = (float)x - 255.5f, Y = (float)y - 255.5f;
  float acc = 0.f;
  #pragma unroll 6
  for (int a=0;a<AANG;a++){
    float sidx = fmaf(X, strig[a], fmaf(Y, strig[AANG+a], 364.0f));
    float ff = floorf(sidx);
    int k = (int)ff - sbase[a];
    float fi = sidx - ff;
    float v0 = sh[a*28+k], v1 = sh[a*28+k+1];
    acc += v0 + fi*(v1-v0);
  }
  unsigned p = pack_hilo(acc);
  size_t p8 = ((size_t)(y*SS + x))*8 + 5;
  hi8[p8] = (unsigned short)(p >> 16);
  lo8[p8] = (unsigned short)(p & 0xffffu);
}

// ---------------- dual conv1 (7->32): MFMA, 4 waves/block (wave = 16-px m-subtile) ----------------
__global__ __launch_bounds__(256) void dual1_mfma(
    const unsigned short* __restrict__ hi8, const unsigned short* __restrict__ lo8,  // [62][DRS][8]
    const unsigned short* __restrict__ Bimg1d,   // this layer: [3][2][2][64][8]
    const float* __restrict__ bias, const float* __restrict__ prelu,
    unsigned short* __restrict__ outHi, unsigned short* __restrict__ outLo)
{
  __shared__ unsigned int tr[64][33];
  int y  = blockIdx.y;                 // 0..59
  int tid = (int)threadIdx.x;
  int wv = tid >> 6, lane = tid & 63;
  int xw = blockIdx.x*64;              // 0..704
  int lm = lane & 15, lq = lane >> 4;
  f32x4 acc0 = (f32x4)0.f, acc1 = (f32x4)0.f;
  const short8* Bf = (const short8*)Bimg1d;
  #pragma unroll
  for (int g=0; g<3; g++){
    const short8* bp8 = Bf + g*256 + lane;
    short8 bh0 = bp8[0], bl0 = bp8[64], bh1 = bp8[128], bl1 = bp8[192];
    int t = g*4 + lq; if (t > 8) t = 8;
    int dy = (t >= 6) ? 1 : ((t >= 3) ? 0 : -1);
    int dx = t - (dy+1)*3 - 1;
    int row = y + dy + 1;              // +1 guard-row offset
    int px = xw + wv*16 + lm + dx;
    size_t off = (size_t)(row*DRS + px)*8;
    short8 ah = *(const short8*)(hi8 + off);
    short8 al = *(const short8*)(lo8 + off);
    acc0 = __builtin_amdgcn_mfma_f32_16x16x32_bf16(ah, bh0, acc0, 0,0,0);
    acc1 = __builtin_amdgcn_mfma_f32_16x16x32_bf16(ah, bh1, acc1, 0,0,0);
    acc0 = __builtin_amdgcn_mfma_f32_16x16x32_bf16(al, bh0, acc0, 0,0,0);
    acc1 = __builtin_amdgcn_mfma_f32_16x16x32_bf16(al, bh1, acc1, 0,0,0);
    acc0 = __builtin_amdgcn_mfma_f32_16x16x32_bf16(ah, bl0, acc0, 0,0,0);
    acc1 = __builtin_amdgcn_mfma_f32_16x16x32_bf16(ah, bl1, acc1, 0,0,0);
  }
  // epilogue: bias + prelu + LDS transpose -> NHWC32 hi/lo (store-masked x<=728)
  float aa = *prelu;
  #pragma unroll
  for (int n=0;n<2;n++){
    int o = n*16 + lm;
    float bv = bias[o];
    f32x4 v = n ? acc1 : acc0;
    v.x+=bv; v.y+=bv; v.z+=bv; v.w+=bv;
    v.x=(v.x>=0.f)?v.x:aa*v.x; v.y=(v.y>=0.f)?v.y:aa*v.y;
    v.z=(v.z>=0.f)?v.z:aa*v.z; v.w=(v.w>=0.f)?v.w:aa*v.w;
    #pragma unroll
    for (int r=0;r<4;r++) tr[wv*16 + lq*4 + r][o] = pack_hilo(v[r]);
  }
  __syncthreads();
  {
    int c8 = tid & 3;
    int px = tid >> 2;
    int x = xw + px;
    if (x <= 728){
      short8 vh, vl;
      #pragma unroll
      for (int j=0;j<8;j++){
        unsigned p = tr[px][c8*8 + j];
        vh[j] = (short)(p >> 16);
        vl[j] = (short)(p & 0xffffu);
      }
      size_t base = ((size_t)(y+1)*DRS + x)*32 + c8*8;
      *(short8*)(outHi + base) = vh;
      *(short8*)(outLo + base) = vl;
    }
  }
}

// ---------------- dual conv2 (32->32): MFMA, 4 waves/block, NHWC32 bf16 hi/lo out ----------------
__global__ __launch_bounds__(256) void dual_mfma32(
    const unsigned short* __restrict__ hiB, const unsigned short* __restrict__ loB,
    const unsigned short* __restrict__ Bimg,   // this layer: [9][2][2][64][8]
    const float* __restrict__ bias, const float* __restrict__ prelu,
    unsigned short* __restrict__ outHi, unsigned short* __restrict__ outLo)
{
  __shared__ unsigned int tr[64][33];
  int y  = blockIdx.y;                               // 0..59
  int tid = (int)threadIdx.x;
  int wv = tid >> 6, lane = tid & 63;
  int xw = blockIdx.x*64;                            // 0..704 step 64
  int lm = lane & 15, lq = lane >> 4;
  int laneoff = lm*32 + lq*8;
  f32x4 acc0 = (f32x4)0.f, acc1 = (f32x4)0.f;
  const short8* Bf = (const short8*)Bimg;
  #pragma unroll
  for (int dy=-1; dy<=1; dy++){
    const unsigned short* rh = hiB + (size_t)(y+dy+1)*DRS*32;
    const unsigned short* rl = loB + (size_t)(y+dy+1)*DRS*32;
    #pragma unroll
    for (int dx=-1; dx<=1; dx++){
      int tap = (dy+1)*3 + (dx+1);
      const short8* bp8 = Bf + tap*256 + lane;
      short8 bh0 = bp8[0], bl0 = bp8[64], bh1 = bp8[128], bl1 = bp8[192];
      int xoff = (xw + dx)*32 + laneoff + wv*512;
      short8 ah = *(const short8*)(rh + xoff);
      short8 al = *(const short8*)(rl + xoff);
      acc0 = __builtin_amdgcn_mfma_f32_16x16x32_bf16(ah, bh0, acc0, 0,0,0);
      acc1 = __builtin_amdgcn_mfma_f32_16x16x32_bf16(ah, bh1, acc1, 0,0,0);
      acc0 = __builtin_amdgcn_mfma_f32_16x16x32_bf16(al, bh0, acc0, 0,0,0);
      acc1 = __builtin_amdgcn_mfma_f32_16x16x32_bf16(al, bh1, acc1, 0,0,0);
      acc0 = __builtin_amdgcn_mfma_f32_16x16x32_bf16(ah, bl0, acc0, 0,0,0);
      acc1 = __builtin_amdgcn_mfma_f32_16x16x32_bf16(ah, bl1, acc1, 0,0,0);
    }
  }
  // epilogue: bias + prelu + LDS transpose -> NHWC32 hi/lo (store-masked x<=728)
  float aa = *prelu;
  #pragma unroll
  for (int n=0;n<2;n++){
    int o = n*16 + lm;
    float bv = bias[o];
    f32x4 v = n ? acc1 : acc0;
    v.x+=bv; v.y+=bv; v.z+=bv; v.w+=bv;
    v.x=(v.x>=0.f)?v.x:aa*v.x; v.y=(v.y>=0.f)?v.y:aa*v.y;
    v.z=(v.z>=0.f)?v.z:aa*v.z; v.w=(v.w>=0.f)?v.w:aa*v.w;
    #pragma unroll
    for (int r=0;r<4;r++) tr[wv*16 + lq*4 + r][o] = pack_hilo(v[r]);
  }
  __syncthreads();
  {
    int c8 = tid & 3;
    int px = tid >> 2;
    int x = xw + px;
    if (x <= 728){
      short8 vh, vl;
      #pragma unroll
      for (int j=0;j<8;j++){
        unsigned p = tr[px][c8*8 + j];
        vh[j] = (short)(p >> 16);
        vl[j] = (short)(p & 0xffffu);
      }
      size_t base = ((size_t)(y+1)*DRS + x)*32 + c8*8;
      *(short8*)(outHi + base) = vh;
      *(short8*)(outLo + base) = vl;
    }
  }
}

// ---------------- dual conv3 (32->5): MFMA N=16, 4 waves/block; h += ; writes s8 ch0-4 ----------------
__global__ __launch_bounds__(256) void dual3_mfma(
    const unsigned short* __restrict__ hiB, const unsigned short* __restrict__ loB,  // NHWC32 [62][DRS][32]
    const unsigned short* __restrict__ Bimg3d,   // this layer: [9][2][64][8]
    const float* __restrict__ bias,
    float* __restrict__ h,
    unsigned short* __restrict__ s8hi, unsigned short* __restrict__ s8lo)
{
  __shared__ unsigned int t8[64][6];
  int y  = blockIdx.y;                               // 0..59
  int tid = (int)threadIdx.x;
  int wv = tid >> 6, lane = tid & 63;
  int xw = blockIdx.x*64;                            // 0..704
  int lm = lane & 15, lq = lane >> 4;
  int laneoff = lm*32 + lq*8;
  f32x4 acc = (f32x4)0.f;
  const short8* Bf = (const short8*)Bimg3d;
  #pragma unroll
  for (int dy=-1; dy<=1; dy++){
    const unsigned short* rh = hiB + (size_t)(y+dy+1)*DRS*32;
    const unsigned short* rl = loB + (size_t)(y+dy+1)*DRS*32;
    #pragma unroll
    for (int dx=-1; dx<=1; dx++){
      int tap = (dy+1)*3 + (dx+1);
      const short8* bp8 = Bf + tap*128 + lane;
      short8 bh = bp8[0];
      short8 bl = bp8[64];
      int xoff = (xw + dx)*32 + laneoff + wv*512;
      short8 ah = *(const short8*)(rh + xoff);
      short8 al = *(const short8*)(rl + xoff);
      acc = __builtin_amdgcn_mfma_f32_16x16x32_bf16(ah, bh, acc, 0,0,0);
      acc = __builtin_amdgcn_mfma_f32_16x16x32_bf16(al, bh, acc, 0,0,0);
      acc = __builtin_amdgcn_mfma_f32_16x16x32_bf16(ah, bl, acc, 0,0,0);
    }
  }
  // epilogue: h += conv3 + bias (lanes lm<5, guarded); pack updated h into LDS
  if (lm < 5){
    float bv = bias[lm];
    int px0 = xw + wv*16 + lq*4;
    float* op = h + (size_t)lm*NSIN + y*DDET + px0;
    float nv0=0.f, nv1=0.f, nv2=0.f, nv3=0.f;
    if (px0 + 3 <= 728){
      v4u old = *(const v4u*)op;
      nv0 = old.x + acc.x + bv;
      nv1 = old.y + acc.y + bv;
      nv2 = old.z + acc.z + bv;
      nv3 = old.w + acc.w + bv;
      v4u st; st.x=nv0; st.y=nv1; st.z=nv2; st.w=nv3;
      *(v4u*)op = st;
    } else {
      if (px0   <= 728){ nv0 = op[0] + acc.x + bv; op[0] = nv0; }
      if (px0+1 <= 728){ nv1 = op[1] + acc.y + bv; op[1] = nv1; }
      if (px0+2 <= 728){ nv2 = op[2] + acc.z + bv; op[2] = nv2; }
      if (px0+3 <= 728){ nv3 = op[3] + acc.w + bv; op[3] = nv3; }
    }
    float nv[4] = {nv0,nv1,nv2,nv3};
    #pragma unroll
    for (int r=0;r<4;r++) t8[wv*16 + lq*4 + r][lm] = pack_hilo(nv[r]);
  }
  __syncthreads();
  // readout: tid<64 = px; write NHWC8 ch0-4 (masked x<=728)
  if (tid < 64){
    int x = xw + tid;
    if (x <= 728){
      unsigned c0 = t8[tid][0], c1 = t8[tid][1], c2 = t8[tid][2];
      unsigned c3 = t8[tid][3], c4 = t8[tid][4];
      size_t base = ((size_t)(y+1)*DRS + x)*8;
      short4v vh; vh[0]=(short)(c0>>16); vh[1]=(short)(c1>>16); vh[2]=(short)(c2>>16); vh[3]=(short)(c3>>16);
      short4v vl; vl[0]=(short)(c0&0xffffu); vl[1]=(short)(c1&0xffffu); vl[2]=(short)(c2&0xffffu); vl[3]=(short)(c3&0xffffu);
      *(short4v*)(s8hi + base) = vh;
      *(short4v*)(s8lo + base) = vl;
      s8hi[base+4] = (unsigned short)(c4>>16);
      s8lo[base+4] = (unsigned short)(c4&0xffffu);
    }
  }
}

// ---------------- primal conv1 (6->32): implicit-GEMM MFMA on NHWC8 input ----------------
__global__ __launch_bounds__(256) void prim1_mfma(
    const unsigned short* __restrict__ hi8, const unsigned short* __restrict__ lo8,  // [512][512][8]
    const unsigned short* __restrict__ Bimg1,   // this layer: [3][2][2][64][8]
    const float* __restrict__ bias, const float* __restrict__ prelu,
    unsigned short* __restrict__ outHi, unsigned short* __restrict__ outLo)
{
  __shared__ unsigned int tr[4][64][33];
  int b = blockIdx.x;                 // 0..1023
  int by = b >> 1, half = b & 1;
  int y = ((by & 7) << 6) | (by >> 3);   // XCD row swizzle
  int wv = (int)threadIdx.x >> 6;
  int lane = (int)threadIdx.x & 63;
  int xw = half*256 + wv*64;
  int lm = lane & 15, lq = lane >> 4;
  f32x4 acc[4][2];
  #pragma unroll
  for (int s=0;s<4;s++){ acc[s][0] = (f32x4)0.f; acc[s][1] = (f32x4)0.f; }
  bool fast = (y>0) && (y<511) && (xw!=0) && (xw!=448);
  const short8* Bf = (const short8*)Bimg1;
  #pragma unroll
  for (int g=0; g<3; g++){
    const short8* bp8 = Bf + g*256 + lane;
    short8 bh0 = bp8[0];
    short8 bl0 = bp8[64];
    short8 bh1 = bp8[128];
    short8 bl1 = bp8[192];
    int t = g*4 + lq; if (t > 8) t = 8;
    int dy = (t >= 6) ? 1 : ((t >= 3) ? 0 : -1);
    int dx = t - (dy+1)*3 - 1;
    int row = y + dy;
    #pragma unroll
    for (int s=0; s<4; s++){
      short8 ah, al;
      int px = xw + s*16 + lm + dx;
      if (fast){
        size_t off = ((size_t)row*SS + px)*8;
        ah = *(const short8*)(hi8 + off);
        al = *(const short8*)(lo8 + off);
      } else {
        bool ok = ((unsigned)row < 512u) && ((unsigned)px < 512u);
        size_t off = ok ? ((size_t)row*SS + px)*8 : 0;
        ah = ok ? *(const short8*)(hi8 + off) : (short8)0;
        al = ok ? *(const short8*)(lo8 + off) : (short8)0;
      }
      acc[s][0] = __builtin_amdgcn_mfma_f32_16x16x32_bf16(ah, bh0, acc[s][0], 0,0,0);
      acc[s][1] = __builtin_amdgcn_mfma_f32_16x16x32_bf16(ah, bh1, acc[s][1], 0,0,0);
      acc[s][0] = __builtin_amdgcn_mfma_f32_16x16x32_bf16(al, bh0, acc[s][0], 0,0,0);
      acc[s][1] = __builtin_amdgcn_mfma_f32_16x16x32_bf16(al, bh1, acc[s][1], 0,0,0);
      acc[s][0] = __builtin_amdgcn_mfma_f32_16x16x32_bf16(ah, bl0, acc[s][0], 0,0,0);
      acc[s][1] = __builtin_amdgcn_mfma_f32_16x16x32_bf16(ah, bl1, acc[s][1], 0,0,0);
    }
  }
  // epilogue: bias + prelu + pack hi/lo into LDS [px][ch], NHWC32 stores
  float aa = *prelu;
  #pragma unroll
  for (int s=0;s<4;s++){
    #pragma unroll
    for (int n=0;n<2;n++){
      int o = n*16 + lm;
      float bv = bias[o];
      f32x4 v = acc[s][n];
      v.x+=bv; v.y+=bv; v.z+=bv; v.w+=bv;
      v.x=(v.x>=0.f)?v.x:aa*v.x; v.y=(v.y>=0.f)?v.y:aa*v.y;
      v.z=(v.z>=0.f)?v.z:aa*v.z; v.w=(v.w>=0.f)?v.w:aa*v.w;
      #pragma unroll
      for (int r=0;r<4;r++)
        tr[wv][s*16 + lq*4 + r][o] = pack_hilo(v[r]);
    }
  }
  __syncthreads();
  int c8 = lane & 3;
  int pxl = lane >> 2;
  #pragma unroll
  for (int k=0;k<4;k++){
    int px = pxl + k*16;
    short8 vh, vl;
    #pragma unroll
    for (int j=0;j<8;j++){
      unsigned p = tr[wv][px][c8*8 + j];
      vh[j] = (short)(p >> 16);
      vl[j] = (short)(p & 0xffffu);
    }
    size_t base = ((size_t)(y*SS + xw + px))*32 + c8*8;
    *(short8*)(outHi + base) = vh;
    *(short8*)(outLo + base) = vl;
  }
}

// ---------------- primal conv2 (32->32): implicit-GEMM MFMA bf16 hi/lo ----------------
__global__ __launch_bounds__(256) void conv_mfma32(
    const unsigned short* __restrict__ hiB, const unsigned short* __restrict__ loB,
    const unsigned short* __restrict__ Bimg,   // this layer: [9][2][2][64][8]
    const float* __restrict__ bias, const float* __restrict__ prelu,
    unsigned short* __restrict__ outHi, unsigned short* __restrict__ outLo)
{
  __shared__ unsigned int tr[4][64][33];
  int b = blockIdx.x;                 // 0..1023
  int by = b >> 1, half = b & 1;
  int y = ((by & 7) << 6) | (by >> 3);   // XCD row swizzle
  int wv = (int)threadIdx.x >> 6;
  int lane = (int)threadIdx.x & 63;
  int xw = half*256 + wv*64;
  int lm = lane & 15, lq = lane >> 4;
  int laneoff = lm*32 + lq*8;
  f32x4 acc[4][2];
  #pragma unroll
  for (int s=0;s<4;s++){ acc[s][0] = (f32x4)0.f; acc[s][1] = (f32x4)0.f; }
  bool fastx = (xw != 0) && (xw != 448);
  const short8* Bf = (const short8*)Bimg;
  #pragma unroll
  for (int dy=-1; dy<=1; dy++){
    int yy = y + dy;
    if ((unsigned)yy >= 512u) continue;
    const unsigned short* rh = hiB + (size_t)yy*512*32;
    const unsigned short* rl = loB + (size_t)yy*512*32;
    #pragma unroll
    for (int dx=-1; dx<=1; dx++){
      int tap = (dy+1)*3 + (dx+1);
      const short8* bp8 = Bf + tap*256 + lane;
      short8 bh0 = bp8[0];     // n=0 hi
      short8 bl0 = bp8[64];    // n=0 lo
      short8 bh1 = bp8[128];   // n=1 hi
      short8 bl1 = bp8[192];   // n=1 lo
      int xoff = (xw + dx)*32 + laneoff;
      #pragma unroll
      for (int s=0; s<4; s++){
        short8 ah, al;
        const unsigned short* ph = rh + xoff + s*512;
        const unsigned short* pl = rl + xoff + s*512;
        if (fastx){
          ah = *(const short8*)ph;
          al = *(const short8*)pl;
        } else {
          int x = xw + s*16 + lm + dx;
          bool ok = ((unsigned)x < 512u);
          ah = ok ? *(const short8*)ph : (short8)0;
          al = ok ? *(const short8*)pl : (short8)0;
        }
        acc[s][0] = __builtin_amdgcn_mfma_f32_16x16x32_bf16(ah, bh0, acc[s][0], 0,0,0);
        acc[s][1] = __builtin_amdgcn_mfma_f32_16x16x32_bf16(ah, bh1, acc[s][1], 0,0,0);
        acc[s][0] = __builtin_amdgcn_mfma_f32_16x16x32_bf16(al, bh0, acc[s][0], 0,0,0);
        acc[s][1] = __builtin_amdgcn_mfma_f32_16x16x32_bf16(al, bh1, acc[s][1], 0,0,0);
        acc[s][0] = __builtin_amdgcn_mfma_f32_16x16x32_bf16(ah, bl0, acc[s][0], 0,0,0);
        acc[s][1] = __builtin_amdgcn_mfma_f32_16x16x32_bf16(ah, bl1, acc[s][1], 0,0,0);
      }
    }
  }
  // epilogue: bias + prelu + pack hi/lo into LDS [px][ch]
  float aa = *prelu;
  #pragma unroll
  for (int s=0;s<4;s++){
    #pragma unroll
    for (int n=0;n<2;n++){
      int o = n*16 + lm;
      float bv = bias[o];
      f32x4 v = acc[s][n];
      v.x+=bv; v.y+=bv; v.z+=bv; v.w+=bv;
      v.x=(v.x>=0.f)?v.x:aa*v.x; v.y=(v.y>=0.f)?v.y:aa*v.y;
      v.z=(v.z>=0.f)?v.z:aa*v.z; v.w=(v.w>=0.f)?v.w:aa*v.w;
      #pragma unroll
      for (int r=0;r<4;r++)
        tr[wv][s*16 + lq*4 + r][o] = pack_hilo(v[r]);
    }
  }
  __syncthreads();
  // read channel-contiguous, split, coalesced NHWC stores
  int c8 = lane & 3;             // 8-channel chunk
  int pxl = lane >> 2;           // 0..15
  #pragma unroll
  for (int k=0;k<4;k++){
    int px = pxl + k*16;
    short8 vh, vl;
    #pragma unroll
    for (int j=0;j<8;j++){
      unsigned p = tr[wv][px][c8*8 + j];
      vh[j] = (short)(p >> 16);
      vl[j] = (short)(p & 0xffffu);
    }
    size_t base = ((size_t)(y*SS + xw + px))*32 + c8*8;
    *(short8*)(outHi + base) = vh;
    *(short8*)(outLo + base) = vl;
  }
}

// ---------------- primal conv3 (32->5): implicit-GEMM MFMA, N=16 (5 real) ----------------
__global__ __launch_bounds__(256) void duo_mfma(
    const unsigned short* __restrict__ hiB, const unsigned short* __restrict__ loB,
    const unsigned short* __restrict__ Bimg3,   // this layer: [9][2][64][8]
    const float* __restrict__ bias,
    float* __restrict__ f,
    float* __restrict__ fout, float* __restrict__ tout,
    unsigned short* __restrict__ hi8, unsigned short* __restrict__ lo8)
{
  __shared__ unsigned int t8[4][64][6];
  int b = blockIdx.x;                 // 0..1023
  int by = b >> 1, half = b & 1;
  int y = ((by & 7) << 6) | (by >> 3);   // XCD row swizzle
  int wv = (int)threadIdx.x >> 6;
  int lane = (int)threadIdx.x & 63;
  int xw = half*256 + wv*64;
  int lm = lane & 15, lq = lane >> 4;
  int laneoff = lm*32 + lq*8;
  f32x4 acc[4];
  #pragma unroll
  for (int s=0;s<4;s++) acc[s] = (f32x4)0.f;
  bool fastx = (xw != 0) && (xw != 448);
  const short8* Bf = (const short8*)Bimg3;
  #pragma unroll
  for (int dy=-1; dy<=1; dy++){
    int yy = y + dy;
    if ((unsigned)yy >= 512u) continue;
    const unsigned short* rh = hiB + (size_t)yy*512*32;
    const unsigned short* rl = loB + (size_t)yy*512*32;
    #pragma unroll
    for (int dx=-1; dx<=1; dx++){
      int tap = (dy+1)*3 + (dx+1);
      const short8* bp8 = Bf + tap*128 + lane;
      short8 bh = bp8[0];
      short8 bl = bp8[64];
      int xoff = (xw + dx)*32 + laneoff;
      #pragma unroll
      for (int s=0; s<4; s++){
        short8 ah, al;
        const unsigned short* ph = rh + xoff + s*512;
        const unsigned short* pl = rl + xoff + s*512;
        if (fastx){
          ah = *(const short8*)ph;
          al = *(const short8*)pl;
        } else {
          int x = xw + s*16 + lm + dx;
          bool ok = ((unsigned)x < 512u);
          ah = ok ? *(const short8*)ph : (short8)0;
          al = ok ? *(const short8*)pl : (short8)0;
        }
        acc[s] = __builtin_amdgcn_mfma_f32_16x16x32_bf16(ah, bh, acc[s], 0,0,0);
        acc[s] = __builtin_amdgcn_mfma_f32_16x16x32_bf16(al, bh, acc[s], 0,0,0);
        acc[s] = __builtin_amdgcn_mfma_f32_16x16x32_bf16(ah, bl, acc[s], 0,0,0);
      }
    }
  }
  // epilogue: f += conv3 + bias on lanes lm<5; imgT transpose (lm==1); output rep (lm==0)
  if (lm < 5){
    float bv = bias[lm];
    #pragma unroll
    for (int s=0;s<4;s++){
      int px0 = xw + s*16 + lq*4;
      float* op = f + (size_t)lm*NPIX + y*SS + px0;
      f32x4 old = *(const f32x4*)op;
      f32x4 v = acc[s];
      v.x += old.x + bv; v.y += old.y + bv;
      v.z += old.z + bv; v.w += old.w + bv;
      *(f32x4*)op = v;
      #pragma unroll
      for (int r=0;r<4;r++)
        t8[wv][s*16 + lq*4 + r][lm] = pack_hilo(v[r]);
      if (lm == 1){
        tout[(px0  )*SS + y] = v.x;
        tout[(px0+1)*SS + y] = v.y;
        tout[(px0+2)*SS + y] = v.z;
        tout[(px0+3)*SS + y] = v.w;
      }
      if (lm == 0 && fout){
        float* q = fout + y*SS + px0;
        *(f32x4*)q = v;
        *(f32x4*)(q + NPIX) = v;
        *(f32x4*)(q + 2*NPIX) = v;
      }
    }
  }
  __syncthreads();
  // readout: lane = px; write NHWC8 ch0-4 (8B + 2B stores, hi and lo)
  {
    unsigned c0 = t8[wv][lane][0], c1 = t8[wv][lane][1], c2 = t8[wv][lane][2];
    unsigned c3 = t8[wv][lane][3], c4 = t8[wv][lane][4];
    size_t base = ((size_t)(y*SS + xw + lane))*8;
    short4v vh; vh[0]=(short)(c0>>16); vh[1]=(short)(c1>>16); vh[2]=(short)(c2>>16); vh[3]=(short)(c3>>16);
    short4v vl; vl[0]=(short)(c0&0xffffu); vl[1]=(short)(c1&0xffffu); vl[2]=(short)(c2&0xffffu); vl[3]=(short)(c3&0xffffu);
    *(short4v*)(hi8 + base) = vh;
    *(short4v*)(lo8 + base) = vl;
    hi8[base+4] = (unsigned short)(c4>>16);
    lo8[base+4] = (unsigned short)(c4&0xffffu);
  }
}

extern "C" void kernel_launch(void* const* d_in, const int* in_sizes, int n_in,
                              void* d_out, int out_size, void* d_ws, size_t ws_size,
                              hipStream_t stream){
  const float* g     = (const float*)d_in[2];
  const float* theta = (const float*)d_in[3];
  const float* dw1 = (const float*)d_in[5];
  const float* db1 = (const float*)d_in[6];
  const float* da1 = (const float*)d_in[7];
  const float* dw2 = (const float*)d_in[8];
  const float* db2 = (const float*)d_in[9];
  const float* da2 = (const float*)d_in[10];
  const float* dw3 = (const float*)d_in[11];
  const float* db3 = (const float*)d_in[12];
  const float* pw1 = (const float*)d_in[13];
  const float* pb1 = (const float*)d_in[14];
  const float* pa1 = (const float*)d_in[15];
  const float* pw2 = (const float*)d_in[16];
  const float* pb2 = (const float*)d_in[17];
  const float* pa2 = (const float*)d_in[18];
  const float* pw3 = (const float*)d_in[19];
  const float* pb3 = (const float*)d_in[20];

  float* ws     = (float*)d_ws;
  float* trig   = ws;                    // 128
  float* taps   = ws + 128;              // -> 2048
  float* h      = ws + 2048;             // 5*NSIN
  float* opf    = h + 5*NSIN;            // NSIN (unused, keeps layout)
  float* gcopy  = opf + NSIN;            // NSIN (unused, keeps layout)
  float* h1     = gcopy + NSIN;          // NSIN
  float* f      = h1 + NSIN;             // 5*NPIX
  float* bp     = f + 5*NPIX;            // NPIX (unused, keeps layout)
  float* imgT   = bp + NPIX;             // NPIX
  float* dualT1 = imgT + NPIX;           // 32*NSIN slot -> dual2Hi
  float* dualT2 = dualT1 + 32*NSIN;      // 32*NSIN slot -> dual2Lo
  float* primT2slot = dualT2 + 32*NSIN;  // 32*NPIX floats of space
  unsigned short* primHi = (unsigned short*)primT2slot;          // 32*NPIX ushorts
  unsigned short* primLo = primHi + (size_t)32*NPIX;             // 32*NPIX ushorts
  unsigned short* nhwcHi = (unsigned short*)(primT2slot + 32*NPIX);  // 32*NPIX ushorts
  unsigned short* nhwcLo = nhwcHi + (size_t)32*NPIX;             // 32*NPIX ushorts
  float* wsp   = (float*)(nhwcLo + (size_t)32*NPIX);
  unsigned short* Bimg  = (unsigned short*)(wsp + 158400);       // 184320 ushorts
  unsigned short* Bimg2 = Bimg + 184320;                         // 184320 ushorts
  unsigned short* Bimg3 = Bimg2 + 184320;                        // 92160 ushorts
  unsigned short* Bimg1 = Bimg3 + 92160;                         // 61440 ushorts
  unsigned short* Bimg1d = Bimg1 + 61440;                        // 61440 ushorts
  unsigned short* Bimg3d = Bimg1d + 61440;                       // 92160 ushorts
  // dual NHWC32 hi/lo: 62 rows x DRS x 32ch + 64-ushort zero prefix/suffix
  const size_t DUALSZ = (size_t)64 + (size_t)62*DRS*32 + 64;
  unsigned short* dualHiRaw = Bimg3d + 92160;
  unsigned short* dualLoRaw = dualHiRaw + DUALSZ;
  unsigned short* dualHi = dualHiRaw + 64;
  unsigned short* dualLo = dualLoRaw + 64;
  // dual conv2 NHWC32 output in recycled dualT1/dualT2 slots
  unsigned short* dual2HiRaw = (unsigned short*)dualT1;
  unsigned short* dual2LoRaw = (unsigned short*)dualT2;
  unsigned short* dual2Hi = dual2HiRaw + 64;
  unsigned short* dual2Lo = dual2LoRaw + 64;
  // primal NHWC8 input image [512][512][8] bf16 hi/lo
  unsigned short* nh8Hi = dualLoRaw + DUALSZ;
  unsigned short* nh8Lo = nh8Hi + (size_t)NPIX*8;
  // sinogram NHWC8 input image [62][DRS][8] bf16 hi/lo + 64-ushort prefix/suffix
  const size_t S8SZ = (size_t)64 + (size_t)62*DRS*8 + 64;
  unsigned short* s8HiRaw = nh8Lo + (size_t)NPIX*8;
  unsigned short* s8LoRaw = s8HiRaw + S8SZ;
  unsigned short* s8Hi = s8HiRaw + 64;
  unsigned short* s8Lo = s8LoRaw + 64;

  hipMemsetAsync(h, 0, (size_t)(5*NSIN)*sizeof(float), stream);
  hipMemsetAsync(f, 0, (size_t)(7*NPIX)*sizeof(float), stream);   // f, bp, imgT
  hipMemsetAsync(dualHiRaw, 0, 2*DUALSZ*sizeof(unsigned short), stream);  // zero pads once
  hipMemsetAsync(dual2HiRaw, 0, DUALSZ*sizeof(unsigned short), stream);   // zero pads once
  hipMemsetAsync(dual2LoRaw, 0, DUALSZ*sizeof(unsigned short), stream);   // zero pads once
  hipMemsetAsync(nh8Hi, 0, (size_t)2*NPIX*8*sizeof(unsigned short), stream); // zero once
  hipMemsetAsync(s8HiRaw, 0, 2*S8SZ*sizeof(unsigned short), stream); // zero once
  trig_kernel<<<1,64,0,stream>>>(theta, trig);
  taps_kernel<<<NTAPS,256,0,stream>>>(taps);
  prep_bimg<<<(92160+255)/256,256,0,stream>>>(pw2, Bimg);
  prep_bimg<<<(92160+255)/256,256,0,stream>>>(dw2, Bimg2);
  prep_bimg3<<<(46080+255)/256,256,0,stream>>>(pw3, Bimg3);
  prep_bimg3<<<(46080+255)/256,256,0,stream>>>(dw3, Bimg3d);
  prep_bimg1c<<<(30720+255)/256,256,0,stream>>>(pw1, Bimg1, 6);
  prep_bimg1c<<<(30720+255)/256,256,0,stream>>>(dw1, Bimg1d, 7);
  g_to_nhwc8<<<(NSIN+255)/256,256,0,stream>>>(g, s8Hi, s8Lo);

  for (int i=0;i<10;i++){
    radon_fwd_kernel<<<(NSIN+3)/4,256,0,stream>>>(f + NPIX, imgT, trig, s8Hi, s8Lo);
    // dual block: NHWC8 [h(5)|opf|g|0] -> conv1 -> conv2 -> conv3 (all MFMA, 4 waves/block)
    dual1_mfma<<<dim3(12,AANG),256,0,stream>>>(s8Hi, s8Lo, Bimg1d+(size_t)i*6144,
                                               db1+(size_t)i*32, da1+i, dualHi, dualLo);
    dual_mfma32<<<dim3(12,AANG),256,0,stream>>>(dualHi, dualLo, Bimg2+(size_t)i*18432,
                                                db2+(size_t)i*32, da2+i, dual2Hi, dual2Lo);
    dual3_mfma<<<dim3(12,AANG),256,0,stream>>>(dual2Hi, dual2Lo, Bimg3d+(size_t)i*9216,
                                               db3+(size_t)i*5, h, s8Hi, s8Lo);
    filter_kernel2<<<AANG*12,256,0,stream>>>(h, taps, h1);
    backproj_kernel<<<NPIX/256,256,0,stream>>>(h1, trig, nh8Hi, nh8Lo);
    // primal block: NHWC8 [f(5)|bp|0|0] -> conv1 -> conv2 -> conv3
    prim1_mfma<<<1024,256,0,stream>>>(nh8Hi, nh8Lo, Bimg1+(size_t)i*6144,
                                      pb1+(size_t)i*32, pa1+i, nhwcHi, nhwcLo);
    conv_mfma32<<<1024,256,0,stream>>>(nhwcHi, nhwcLo, Bimg+(size_t)i*18432, pb2+(size_t)i*32, pa2+i, primHi, primLo);
    duo_mfma<<<1024,256,0,stream>>>(primHi, primLo, Bimg3+(size_t)i*9216, pb3+(size_t)i*5, f,
                                    (i==9) ? (float*)d_out : nullptr, imgT, nh8Hi, nh8Lo);
  }
}